// Round 8
// baseline (343.811 us; speedup 1.0000x reference)
//
#include <hip/hip_runtime.h>
#include <math.h>

typedef unsigned int u32;
typedef unsigned short u16;
using half8 = __attribute__((ext_vector_type(8))) _Float16;
using f32x4 = __attribute__((ext_vector_type(4))) float;

#define NN 20000
#define MPAD 20096          // 157 * 128
#define NE 160000
#define ET 180000           // NE + NN self loops
#define NG 64
#define NBLK 79             // ceil(NN/256)

constexpr float NEG_ATT = 0.2f;
constexpr float NEG_ACT = 0.01f;
constexpr float EPS_GN  = 1e-5f;

struct Ptr4 { const float *p0, *p1, *p2, *p3; };

// ---------- helpers ----------

__device__ __forceinline__ u16 f2h(float f) {
    _Float16 h = (_Float16)f;
    return __builtin_bit_cast(u16, h);
}
__device__ __forceinline__ float h2f(u16 b) {
    return (float)__builtin_bit_cast(_Float16, b);
}

__device__ __forceinline__ void gl_lds16(const void* g, void* l) {
    __builtin_amdgcn_global_load_lds((const __attribute__((address_space(1))) u32*)g,
                                     (__attribute__((address_space(3))) u32*)l, 16, 0, 0);
}

__device__ __forceinline__ float lrelu_att(float v) {
    return (v > 0.f) ? v : NEG_ATT * v;
}

// ---------------- graph bounds via binary search (batch is sorted) ----------------

__global__ void k_bounds(const int* __restrict__ batch, int* __restrict__ counts,
                         int* __restrict__ gstart) {
    __shared__ int ls[NG + 1];
    int g = threadIdx.x;           // 64 threads
    int lo = 0, hi = NN;
    while (lo < hi) {
        int mid = (lo + hi) >> 1;
        if (batch[mid] < g) lo = mid + 1; else hi = mid;
    }
    ls[g] = lo;
    if (g == 0) ls[NG] = NN;
    __syncthreads();
    counts[g] = ls[g + 1] - ls[g];
    gstart[g] = ls[g];
    if (g == 0) gstart[NG] = NN;
}

// ---------------- CSR build ----------------

__global__ void k_deg(const int* __restrict__ ei, int* deg) {
    int i = blockIdx.x * 256 + threadIdx.x;
    if (i >= ET) return;
    int dst = (i < NE) ? ei[NE + i] : (i - NE);
    atomicAdd(&deg[dst], 1);
}

__global__ void k_scan1(const int* __restrict__ deg, int* __restrict__ bsum) {
    int i = blockIdx.x * 256 + threadIdx.x;
    int v = (i < NN) ? deg[i] : 0;
    int lane = threadIdx.x & 63, w = threadIdx.x >> 6;
    #pragma unroll
    for (int off = 32; off; off >>= 1) v += __shfl_down(v, off, 64);
    __shared__ int ws[4];
    if (lane == 0) ws[w] = v;
    __syncthreads();
    if (threadIdx.x == 0) bsum[blockIdx.x] = ws[0] + ws[1] + ws[2] + ws[3];
}

__global__ void k_scan2(const int* __restrict__ bsum, int* __restrict__ boff,
                        int* __restrict__ total) {
    int tid = threadIdx.x;      // 256
    int v = (tid < NBLK) ? bsum[tid] : 0;
    int lane = tid & 63, w = tid >> 6;
    int val = v;
    #pragma unroll
    for (int off = 1; off < 64; off <<= 1) {
        int t = __shfl_up(val, off, 64);
        if (lane >= off) val += t;
    }
    __shared__ int ws[4];
    if (lane == 63) ws[w] = val;
    __syncthreads();
    int woff = 0;
    for (int k = 0; k < w; k++) woff += ws[k];
    int excl = woff + val - v;
    if (tid < NBLK) boff[tid] = excl;
    if (tid == NBLK - 1) *total = excl + v;
}

__global__ void k_scan3(const int* __restrict__ deg, const int* __restrict__ boff,
                        int* __restrict__ row_ptr, int* __restrict__ cursor) {
    int i = blockIdx.x * 256 + threadIdx.x;
    int v = (i < NN) ? deg[i] : 0;
    int lane = threadIdx.x & 63, w = threadIdx.x >> 6;
    int val = v;
    #pragma unroll
    for (int off = 1; off < 64; off <<= 1) {
        int t = __shfl_up(val, off, 64);
        if (lane >= off) val += t;
    }
    __shared__ int ws[4];
    if (lane == 63) ws[w] = val;
    __syncthreads();
    int woff = 0;
    for (int k = 0; k < w; k++) woff += ws[k];
    int excl = boff[blockIdx.x] + woff + val - v;
    if (i < NN) { row_ptr[i] = excl; cursor[i] = excl; }
}

__global__ void k_scatter(const int* __restrict__ ei, int* cursor, int* __restrict__ col) {
    int i = blockIdx.x * 256 + threadIdx.x;
    if (i >= ET) return;
    int s, d;
    if (i < NE) { s = ei[i]; d = ei[NE + i]; } else { s = i - NE; d = s; }
    int p = atomicAdd(&cursor[d], 1);
    col[p] = s;
}

// ---------------- all-layer wsrc = W @ asrc, wdst = W @ adst ----------------

__global__ void k_wvec_all(Ptr4 W, Ptr4 As, Ptr4 Ad,
                           float* __restrict__ wsrcA, float* __restrict__ wdstA) {
    const int dins[4]  = {9, 128, 256, 512};
    const int douts[4] = {128, 256, 512, 1534};
    int l = blockIdx.y, k = blockIdx.x;
    if (k >= dins[l]) return;
    const float* Wp = (l == 0) ? W.p0 : (l == 1) ? W.p1 : (l == 2) ? W.p2 : W.p3;
    const float* as = (l == 0) ? As.p0 : (l == 1) ? As.p1 : (l == 2) ? As.p2 : As.p3;
    const float* ad = (l == 0) ? Ad.p0 : (l == 1) ? Ad.p1 : (l == 2) ? Ad.p2 : Ad.p3;
    int NC = douts[l];
    const float* row = Wp + (size_t)k * NC;
    float ss = 0.f, sd = 0.f;
    for (int n = threadIdx.x; n < NC; n += 256) {
        float w = row[n];
        ss += w * as[n];
        sd += w * ad[n];
    }
    __shared__ float ls[8];
    int lane = threadIdx.x & 63, w4 = threadIdx.x >> 6;
    #pragma unroll
    for (int off = 32; off; off >>= 1) {
        ss += __shfl_down(ss, off, 64);
        sd += __shfl_down(sd, off, 64);
    }
    if (lane == 0) { ls[w4] = ss; ls[4 + w4] = sd; }
    __syncthreads();
    if (threadIdx.x == 0) {
        wsrcA[l * 512 + k] = ls[0] + ls[1] + ls[2] + ls[3];
        wdstA[l * 512 + k] = ls[4] + ls[5] + ls[6] + ls[7];
    }
}

// ---------------- all-layer W transpose + pad + f16 ----------------

__global__ void k_wbt_all(Ptr4 W, u16* __restrict__ WbTall) {
    const int Ks[3] = {128, 256, 512};
    const int NCs[3] = {256, 512, 1534};
    const int Nps[3] = {256, 512, 1536};
    const size_t offs[3] = {0, 256 * 128, 256 * 128 + 512 * 256};
    int l = blockIdx.z;
    int K = Ks[l], NC = NCs[l], Np = Nps[l];
    int n0 = blockIdx.x * 32, k0 = blockIdx.y * 32;
    if (n0 >= Np || k0 >= K) return;
    const float* Wp = (l == 0) ? W.p1 : (l == 1) ? W.p2 : W.p3;
    u16* WbT = WbTall + offs[l];
    __shared__ u16 tile[32][33];
    int tx = threadIdx.x & 31, ty = threadIdx.x >> 5;   // ty 0..7
    #pragma unroll
    for (int i = 0; i < 4; i++) {
        int k = k0 + ty + i * 8, n = n0 + tx;
        float v = (k < K && n < NC) ? Wp[(size_t)k * NC + n] : 0.f;
        tile[ty + i * 8][tx] = f2h(v);
    }
    __syncthreads();
    #pragma unroll
    for (int i = 0; i < 4; i++) {
        int n = n0 + ty + i * 8, k = k0 + tx;
        if (n < Np && k < K) WbT[(size_t)n * K + k] = tile[tx][ty + i * 8];
    }
}

// ---------------- scores ----------------

__global__ void k_scores0(const float* __restrict__ x, const float* __restrict__ wsrc,
                          const float* __restrict__ wdst, float* __restrict__ s_src,
                          float* __restrict__ s_dst) {
    int v = blockIdx.x * 256 + threadIdx.x;
    if (v >= NN) return;
    const float* r = x + (size_t)v * 9;
    float ss = 0.f, sd = 0.f;
    #pragma unroll
    for (int k = 0; k < 9; k++) { ss += r[k] * wsrc[k]; sd += r[k] * wdst[k]; }
    s_src[v] = ss; s_dst[v] = sd;
}

// VW = f16 cols per lane per load: 2 (u32), 4 (uint2), 8 (uint4)
template <int VW>
__global__ void k_scores_h(const u16* __restrict__ h, const float* __restrict__ wsrc,
                           const float* __restrict__ wdst, float* __restrict__ s_src,
                           float* __restrict__ s_dst, int din) {
    int v = blockIdx.x * 4 + (threadIdx.x >> 6);
    int lane = threadIdx.x & 63;
    if (v >= NN) return;
    const u16* row = h + (size_t)v * din;
    float ss = 0.f, sd = 0.f;
    for (int d = lane * VW; d < din; d += 64 * VW) {
        u32 ua[VW / 2];
        if constexpr (VW == 2) {
            ua[0] = *(const u32*)(row + d);
        } else if constexpr (VW == 4) {
            uint2 t = *(const uint2*)(row + d);
            ua[0] = t.x; ua[1] = t.y;
        } else {
            uint4 t = *(const uint4*)(row + d);
            ua[0] = t.x; ua[1] = t.y; ua[2] = t.z; ua[3] = t.w;
        }
        #pragma unroll
        for (int j = 0; j < VW / 2; j++) {
            float h0 = h2f((u16)(ua[j] & 0xffffu)), h1 = h2f((u16)(ua[j] >> 16));
            ss += h0 * wsrc[d + 2 * j] + h1 * wsrc[d + 2 * j + 1];
            sd += h0 * wdst[d + 2 * j] + h1 * wdst[d + 2 * j + 1];
        }
    }
    #pragma unroll
    for (int off = 32; off; off >>= 1) {
        ss += __shfl_down(ss, off, 64);
        sd += __shfl_down(sd, off, 64);
    }
    if (lane == 0) { s_src[v] = ss; s_dst[v] = sd; }
}

// ---------------- edge softmax: alpha per edge (one wave per node) ----------------

__global__ __launch_bounds__(256) void k_alpha(const int* __restrict__ row_ptr,
                                               const int* __restrict__ col,
                                               const float* __restrict__ s_src,
                                               const float* __restrict__ s_dst,
                                               float* __restrict__ alpha) {
    int grp = threadIdx.x >> 6;
    int lane = threadIdx.x & 63;
    int v = blockIdx.x * 4 + grp;
    if (v >= NN) return;
    int st = row_ptr[v], en = row_ptr[v + 1];
    float sd = s_dst[v];
    float mx = -INFINITY;
    for (int p = st + lane; p < en; p += 64)
        mx = fmaxf(mx, lrelu_att(s_src[col[p]] + sd));
    #pragma unroll
    for (int off = 32; off; off >>= 1) mx = fmaxf(mx, __shfl_xor(mx, off, 64));
    float sum = 0.f;
    for (int p = st + lane; p < en; p += 64)
        sum += __expf(lrelu_att(s_src[col[p]] + sd) - mx);
    #pragma unroll
    for (int off = 32; off; off >>= 1) sum += __shfl_xor(sum, off, 64);
    float inv = 1.0f / (sum + 1e-16f);
    for (int p = st + lane; p < en; p += 64)
        alpha[p] = __expf(lrelu_att(s_src[col[p]] + sd) - mx) * inv;
}

// ---------------- chunked gather: agg[v][chunk*64..+64) = sum_e alpha_e * h[col_e] ----------------
// R7 post-mortem: monolithic gather read 184 MB from a 20.5 MB table that fits NEITHER
// per-XCD L2 (4 MiB) nor stays LLC-resident (FETCH 77.7 MB = 3.8x table). Chunk-major
// grid: all concurrently-resident blocks read the same 64-col slab (20000x64x2 = 2.56 MB
// < 4 MiB L2/XCD) -> gather re-reads become L2 hits. 16 threads/node (uint2 = 4 cols),
// 16 nodes/block.

__global__ __launch_bounds__(256) void k_agg_gather(const u16* __restrict__ h,
                                                    const int* __restrict__ row_ptr,
                                                    const int* __restrict__ col,
                                                    const float* __restrict__ alpha,
                                                    u16* __restrict__ agg,
                                                    int din, int nbn) {
    int blk = blockIdx.x;
    int chunk = blk / nbn;            // chunk-major: consecutive blocks share a slab
    int nb = blk % nbn;
    int tg = threadIdx.x >> 4;        // node in block (0..15)
    int lane = threadIdx.x & 15;
    int v = nb * 16 + tg;
    if (v >= NN) return;
    int st = row_ptr[v], en = row_ptr[v + 1];
    int d0 = chunk * 64 + lane * 4;
    const u16* hb = h + d0;
    float a0_, a1_, acc0 = 0.f, acc1 = 0.f, acc2 = 0.f, acc3 = 0.f;
    int p = st;
    for (; p + 2 <= en; p += 2) {
        int c0 = col[p], c1 = col[p + 1];
        a0_ = alpha[p]; a1_ = alpha[p + 1];
        uint2 t0 = *(const uint2*)(hb + (size_t)c0 * din);
        uint2 t1 = *(const uint2*)(hb + (size_t)c1 * din);
        acc0 += a0_ * h2f((u16)(t0.x & 0xffffu)) + a1_ * h2f((u16)(t1.x & 0xffffu));
        acc1 += a0_ * h2f((u16)(t0.x >> 16))     + a1_ * h2f((u16)(t1.x >> 16));
        acc2 += a0_ * h2f((u16)(t0.y & 0xffffu)) + a1_ * h2f((u16)(t1.y & 0xffffu));
        acc3 += a0_ * h2f((u16)(t0.y >> 16))     + a1_ * h2f((u16)(t1.y >> 16));
    }
    if (p < en) {
        int c0 = col[p];
        a0_ = alpha[p];
        uint2 t0 = *(const uint2*)(hb + (size_t)c0 * din);
        acc0 += a0_ * h2f((u16)(t0.x & 0xffffu));
        acc1 += a0_ * h2f((u16)(t0.x >> 16));
        acc2 += a0_ * h2f((u16)(t0.y & 0xffffu));
        acc3 += a0_ * h2f((u16)(t0.y >> 16));
    }
    uint2 ov;
    ov.x = (u32)f2h(acc0) | ((u32)f2h(acc1) << 16);
    ov.y = (u32)f2h(acc2) | ((u32)f2h(acc3) << 16);
    *(uint2*)(agg + (size_t)v * din + d0) = ov;
}

// layer-0 variant: din=9, f32 input; one wave per node, lanes 0..8 gather.
__global__ __launch_bounds__(256) void k_agg0_fused(const float* __restrict__ x,
                                                    const int* __restrict__ row_ptr,
                                                    const int* __restrict__ col,
                                                    const float* __restrict__ s_src,
                                                    const float* __restrict__ s_dst,
                                                    float* __restrict__ agg0) {
    __shared__ float sm[4 * 2];
    int grp = threadIdx.x >> 6;
    int lane = threadIdx.x & 63;
    int v = blockIdx.x * 4 + grp;
    bool valid = v < NN;
    int st = 0, en = 0;
    float sd = 0.f;
    if (valid) { st = row_ptr[v]; en = row_ptr[v + 1]; sd = s_dst[v]; }
    float mx = -INFINITY;
    if (valid) {
        for (int p = st + lane; p < en; p += 64)
            mx = fmaxf(mx, lrelu_att(s_src[col[p]] + sd));
    }
    #pragma unroll
    for (int off = 32; off; off >>= 1) mx = fmaxf(mx, __shfl_xor(mx, off, 64));
    float sum = 0.f;
    if (valid) {
        for (int p = st + lane; p < en; p += 64)
            sum += __expf(lrelu_att(s_src[col[p]] + sd) - mx);
    }
    #pragma unroll
    for (int off = 32; off; off >>= 1) sum += __shfl_xor(sum, off, 64);
    if (lane == 0) { sm[grp * 2] = mx; sm[grp * 2 + 1] = 1.0f / (sum + 1e-16f); }
    __syncthreads();
    if (!valid || lane >= 9) return;
    float m = sm[grp * 2], inv = sm[grp * 2 + 1];
    float acc = 0.f;
    for (int p = st; p < en; p++) {
        int c = col[p];
        float a = __expf(lrelu_att(s_src[c] + sd) - m);
        acc += a * x[(size_t)c * 9 + lane];
    }
    agg0[(size_t)v * 9 + lane] = acc * inv;
}

// ---------------- layer 0 GEMM: agg0[NN][9] f32 @ W0[9][128] + bias + lrelu ----------------

__global__ __launch_bounds__(256) void k_gemm0(const float* __restrict__ agg0,
                                               const float* __restrict__ W,
                                               const float* __restrict__ bias,
                                               u16* __restrict__ out) {
    __shared__ float Ws[9 * 128];
    for (int i = threadIdx.x; i < 9 * 128; i += 256) Ws[i] = W[i];
    __syncthreads();
    int node = blockIdx.x * 2 + (threadIdx.x >> 7);
    int n = threadIdx.x & 127;
    if (node >= NN) return;
    const float* xr = agg0 + (size_t)node * 9;
    float acc = bias[n];
    #pragma unroll
    for (int k = 0; k < 9; k++) acc += xr[k] * Ws[k * 128 + n];
    acc = (acc > 0.f) ? acc : NEG_ACT * acc;
    out[(size_t)node * 128 + n] = f2h(acc);
}

// ---------------- 128x128 MFMA GEMM (kept for layer 1) ----------------

#define BM 128
#define BK 32

__global__ __launch_bounds__(256) void k_gemm_f16(const u16* __restrict__ A,
                                                  const u16* __restrict__ B,
                                                  const float* __restrict__ bias,
                                                  u16* __restrict__ C,
                                                  int K, int ldC, int NC, int ntx) {
    int nwg = gridDim.x;
    int b = blockIdx.x;
    int q = nwg >> 3, r = nwg & 7;
    int xcd = b & 7, idx = b >> 3;
    int wg = (xcd < r ? xcd * (q + 1) : r * (q + 1) + (xcd - r) * q) + idx;
    int row0 = (wg / ntx) * BM;
    int col0 = (wg % ntx) * BM;

    __shared__ u16 lds[2][2][BM * BK];   // 32 KiB
    int tid = threadIdx.x;
    int lane = tid & 63, w = tid >> 6;
    int wr = w >> 1, wc = w & 1;

    f32x4 acc[4][4];
    #pragma unroll
    for (int m = 0; m < 4; m++)
        #pragma unroll
        for (int n = 0; n < 4; n++)
            #pragma unroll
            for (int rr2 = 0; rr2 < 4; rr2++) acc[m][n][rr2] = 0.f;

    int nt = K / BK;

    auto stage = [&](int buf, int t) {
        int k0 = t * BK;
        #pragma unroll
        for (int c = 0; c < 2; c++) {
            int idx2 = tid + c * 256;           // 0..511
            int rr2 = idx2 >> 2, kc = idx2 & 3;
            int kcs = kc ^ (rr2 & 3);           // pre-swizzled global source
            gl_lds16(A + (size_t)(row0 + rr2) * K + k0 + kcs * 8, &lds[buf][0][idx2 * 8]);
            gl_lds16(B + (size_t)(col0 + rr2) * K + k0 + kcs * 8, &lds[buf][1][idx2 * 8]);
        }
    };

    auto compute = [&](int buf) {
        const u16* As = &lds[buf][0][0];
        const u16* Bs = &lds[buf][1][0];
        int kg = lane >> 4, rl = lane & 15;
        half8 af[4], bfr[4];
        #pragma unroll
        for (int m = 0; m < 4; m++) {
            int rr2 = wr * 64 + m * 16 + rl;
            af[m] = *(const half8*)(As + rr2 * BK + (kg ^ (rr2 & 3)) * 8);
        }
        #pragma unroll
        for (int n = 0; n < 4; n++) {
            int rr2 = wc * 64 + n * 16 + rl;
            bfr[n] = *(const half8*)(Bs + rr2 * BK + (kg ^ (rr2 & 3)) * 8);
        }
        #pragma unroll
        for (int m = 0; m < 4; m++)
            #pragma unroll
            for (int n = 0; n < 4; n++)
                acc[m][n] = __builtin_amdgcn_mfma_f32_16x16x32_f16(af[m], bfr[n], acc[m][n], 0, 0, 0);
    };

    stage(0, 0);
    __syncthreads();
    for (int t = 0; t < nt; t++) {
        if (t + 1 < nt) stage((t + 1) & 1, t + 1);
        compute(t & 1);
        __syncthreads();
    }

    u16* ep = ((u16*)lds) + w * (32 * 72);
    int kg = lane >> 4, rl = lane & 15;
    int rrow = lane >> 3;
    int c8 = (lane & 7) * 8;
    #pragma unroll
    for (int half = 0; half < 2; half++) {
        #pragma unroll
        for (int m2 = 0; m2 < 2; m2++) {
            int m = half * 2 + m2;
            #pragma unroll
            for (int n = 0; n < 4; n++) {
                int colg = col0 + wc * 64 + n * 16 + rl;
                float bb = (colg < NC) ? bias[colg] : 0.f;
                #pragma unroll
                for (int rr2 = 0; rr2 < 4; rr2++) {
                    float o = acc[m][n][rr2] + bb;
                    o = (o > 0.f) ? o : NEG_ACT * o;
                    ep[(m2 * 16 + kg * 4 + rr2) * 72 + n * 16 + rl] = f2h(o);
                }
            }
        }
        #pragma unroll
        for (int it = 0; it < 4; it++) {
            int rloc = it * 8 + rrow;
            half8 vv = *(const half8*)(ep + rloc * 72 + c8);
            int rowg = row0 + wr * 64 + half * 32 + rloc;
            *(half8*)(C + (size_t)rowg * ldC + col0 + wc * 64 + c8) = vv;
        }
    }
}

// ---------------- 256x256 MFMA GEMM: BK=32, TRIPLE buffer, ONE barrier/K-tile ----------------

__global__ __launch_bounds__(1024, 4) void k_gemm256(const u16* __restrict__ A,
                                                     const u16* __restrict__ B,
                                                     const float* __restrict__ bias,
                                                     u16* __restrict__ C,
                                                     int K, int ldC, int NC, int ntx, int M) {
    __shared__ u16 sMem[49152];   // 3 bufs x (A 8192 + B 8192) u16 = 96 KiB

    int nwg = gridDim.x, b = blockIdx.x;
    int q = nwg >> 3, r = nwg & 7;
    int xcd = b & 7, bidx = b >> 3;
    int wg = (xcd < r ? xcd * (q + 1) : r * (q + 1) + (xcd - r) * q) + bidx;
    int row0 = (wg / ntx) * 256;
    int col0 = (wg % ntx) * 256;

    int tid = threadIdx.x;
    int w = tid >> 6, lane = tid & 63;
    int wm = w >> 2, wn = w & 3;           // 4 x 4 wave grid, 64x64 out per wave
    int rl = lane & 15, kg = lane >> 4;
    int ksl = (kg ^ ((rl >> 1) & 3)) * 8;  // swizzled read slot offset (u16 units)

    f32x4 acc[4][4];
    #pragma unroll
    for (int m = 0; m < 4; m++)
        #pragma unroll
        for (int n = 0; n < 4; n++)
            #pragma unroll
            for (int i = 0; i < 4; i++) acc[m][n][i] = 0.f;

    {
        int rr = tid >> 2, s = tid & 3;
        int ss = s ^ ((rr >> 1) & 3);
        int ra = row0 + rr; ra = (ra < M) ? ra : (M - 1);
        const u16* aSrc0 = A + (size_t)ra * K + ss * 8;
        const u16* bSrc0 = B + (size_t)(col0 + rr) * K + ss * 8;
        u16* dstA = sMem + tid * 8;
        u16* dstB = sMem + 8192 + tid * 8;

        auto stage = [&](int t, int bf2) {
            gl_lds16(aSrc0 + t * 32, dstA + bf2 * 16384);
            gl_lds16(bSrc0 + t * 32, dstB + bf2 * 16384);
        };

        half8 af[4], bf[4];
        auto ldAB = [&](int bf2) {
            const u16* Ab = sMem + bf2 * 16384;
            const u16* Bb = Ab + 8192;
            #pragma unroll
            for (int i = 0; i < 4; i++)
                af[i] = *(const half8*)(Ab + (wm * 64 + i * 16 + rl) * 32 + ksl);
            #pragma unroll
            for (int i = 0; i < 4; i++)
                bf[i] = *(const half8*)(Bb + (wn * 64 + i * 16 + rl) * 32 + ksl);
        };

        int nt = K >> 5;    // K-tiles of 32; nt >= 8 for our shapes

        stage(0, 0); stage(1, 1);
        __builtin_amdgcn_sched_barrier(0);
        asm volatile("s_waitcnt vmcnt(2)" ::: "memory");
        __builtin_amdgcn_s_barrier();
        __builtin_amdgcn_sched_barrier(0);

        int rb = 0;
        for (int t = 0; t < nt; t++) {
            int sb = rb + 2; if (sb >= 3) sb -= 3;
            if (t + 2 < nt) stage(t + 2, sb);
            ldAB(rb);
            __builtin_amdgcn_s_setprio(1);
            #pragma unroll
            for (int i = 0; i < 4; i++)
                #pragma unroll
                for (int n = 0; n < 4; n++)
                    acc[i][n] = __builtin_amdgcn_mfma_f32_16x16x32_f16(af[i], bf[n], acc[i][n], 0, 0, 0);
            __builtin_amdgcn_s_setprio(0);
            __builtin_amdgcn_sched_barrier(0);
            if (t + 2 < nt)      asm volatile("s_waitcnt vmcnt(2)" ::: "memory");
            else if (t + 1 < nt) asm volatile("s_waitcnt vmcnt(0)" ::: "memory");
            __builtin_amdgcn_s_barrier();
            __builtin_amdgcn_sched_barrier(0);
            rb = (rb == 2) ? 0 : rb + 1;
        }
    }

    // epilogue: per-wave private 32x72 LDS staging region, coalesced half8 stores
    u16* ep = sMem + w * (32 * 72);
    float bv[4];
    #pragma unroll
    for (int n = 0; n < 4; n++) {
        int colg = col0 + wn * 64 + n * 16 + rl;
        bv[n] = (colg < NC) ? bias[colg] : 0.f;
    }
    int rrow = lane >> 3, c8 = (lane & 7) * 8;
    #pragma unroll
    for (int mh = 0; mh < 2; mh++) {
        #pragma unroll
        for (int msub = 0; msub < 2; msub++) {
            int m = mh * 2 + msub;
            #pragma unroll
            for (int n = 0; n < 4; n++) {
                #pragma unroll
                for (int rg = 0; rg < 4; rg++) {
                    float o = acc[m][n][rg] + bv[n];
                    o = (o > 0.f) ? o : NEG_ACT * o;
                    ep[(msub * 16 + kg * 4 + rg) * 72 + n * 16 + rl] = f2h(o);
                }
            }
        }
        #pragma unroll
        for (int it = 0; it < 4; it++) {
            int rloc = it * 8 + rrow;
            half8 vv = *(const half8*)(ep + rloc * 72 + c8);
            int rowg = row0 + wm * 64 + mh * 32 + rloc;
            if (rowg < M)
                *(half8*)(C + (size_t)rowg * ldC + col0 + wn * 64 + c8) = vv;
        }
    }
}

// ---------------- GraphNorm fused: stats + apply (or pool) in ONE kernel ----------------

__global__ __launch_bounds__(256) void k_gn_fused(const u16* __restrict__ h,
                           const int* __restrict__ gstart,
                           const float* __restrict__ ms, const float* __restrict__ gam,
                           const float* __restrict__ bet, u16* __restrict__ out, int ld) {
    int g = blockIdx.x;
    int c0 = blockIdx.y * 128;
    int ct = threadIdx.x & 15, rg = threadIdx.x >> 4;
    int d0 = c0 + ct * 8;
    int st = gstart[g], en = gstart[g + 1];
    float inv = 1.0f / (float)(en - st);
    float s[8], qq[8];
    #pragma unroll
    for (int i = 0; i < 8; i++) { s[i] = 0.f; qq[i] = 0.f; }
    for (int r = st + rg; r < en; r += 16) {
        uint4 u = *(const uint4*)(h + (size_t)r * ld + d0);
        u32 ua[4] = {u.x, u.y, u.z, u.w};
        #pragma unroll
        for (int j = 0; j < 4; j++) {
            float v0 = h2f((u16)(ua[j] & 0xffffu)), v1 = h2f((u16)(ua[j] >> 16));
            s[2 * j] += v0; s[2 * j + 1] += v1;
            qq[2 * j] += v0 * v0; qq[2 * j + 1] += v1 * v1;
        }
    }
    __shared__ float Ls[16][128], Lq[16][128];
    #pragma unroll
    for (int i = 0; i < 8; i++) { Ls[rg][ct * 8 + i] = s[i]; Lq[rg][ct * 8 + i] = qq[i]; }
    __syncthreads();
    int tid = threadIdx.x;
    if (tid < 128) {
        float ss = 0.f, sq = 0.f;
        #pragma unroll
        for (int r2 = 1; r2 < 16; r2++) { ss += Ls[r2][tid]; sq += Lq[r2][tid]; }
        Ls[0][tid] += ss; Lq[0][tid] += sq;
    }
    __syncthreads();
    float sub[8], sc[8], bv[8];
    #pragma unroll
    for (int i = 0; i < 8; i++) {
        int cl = ct * 8 + i, d = d0 + i;
        float msv = ms[d];
        float mean = Ls[0][cl] * inv;
        float q2   = Lq[0][cl] * inv;
        float var  = fmaxf(q2 - (2.f * msv - msv * msv) * mean * mean, 0.f);
        sub[i] = msv * mean;
        sc[i]  = gam[d] * rsqrtf(var + EPS_GN);
        bv[i]  = bet[d];
    }
    for (int r = st + rg; r < en; r += 16) {
        uint4 u = *(const uint4*)(h + (size_t)r * ld + d0);
        u32 ua[4] = {u.x, u.y, u.z, u.w};
        uint4 wv4;
        u32 wo[4];
        #pragma unroll
        for (int j = 0; j < 4; j++) {
            float o0 = (h2f((u16)(ua[j] & 0xffffu)) - sub[2 * j]) * sc[2 * j] + bv[2 * j];
            float o1 = (h2f((u16)(ua[j] >> 16)) - sub[2 * j + 1]) * sc[2 * j + 1] + bv[2 * j + 1];
            wo[j] = (u32)f2h(o0) | ((u32)f2h(o1) << 16);
        }
        wv4.x = wo[0]; wv4.y = wo[1]; wv4.z = wo[2]; wv4.w = wo[3];
        *(uint4*)(out + (size_t)r * ld + d0) = wv4;
    }
}

// l=3: fused stats + normalize + mean/max pool, writing d_out directly.
__global__ __launch_bounds__(256) void k_gn_poolf(const u16* __restrict__ h,
                           const int* __restrict__ gstart,
                           const float* __restrict__ ms, const float* __restrict__ gam,
                           const float* __restrict__ bet, float* __restrict__ out,
                           int dout, int ld) {
    int g = blockIdx.x;
    int c0 = blockIdx.y * 128;
    int ct = threadIdx.x & 15, rg = threadIdx.x >> 4;
    int d0 = c0 + ct * 8;
    int st = gstart[g], en = gstart[g + 1];
    float inv = 1.0f / (float)(en - st);
    float s[8], qq[8];
    #pragma unroll
    for (int i = 0; i < 8; i++) { s[i] = 0.f; qq[i] = 0.f; }
    for (int r = st + rg; r < en; r += 16) {
        uint4 u = *(const uint4*)(h + (size_t)r * ld + d0);
        u32 ua[4] = {u.x, u.y, u.z, u.w};
        #pragma unroll
        for (int j = 0; j < 4; j++) {
            float v0 = h2f((u16)(ua[j] & 0xffffu)), v1 = h2f((u16)(ua[j] >> 16));
            s[2 * j] += v0; s[2 * j + 1] += v1;
            qq[2 * j] += v0 * v0; qq[2 * j + 1] += v1 * v1;
        }
    }
    __shared__ float Ls[16][128], Lq[16][128];
    #pragma unroll
    for (int i = 0; i < 8; i++) { Ls[rg][ct * 8 + i] = s[i]; Lq[rg][ct * 8 + i] = qq[i]; }
    __syncthreads();
    int tid = threadIdx.x;
    if (tid < 128) {
        float ss = 0.f, sq = 0.f;
        #pragma unroll
        for (int r2 = 1; r2 < 16; r2++) { ss += Ls[r2][tid]; sq += Lq[r2][tid]; }
        Ls[0][tid] += ss; Lq[0][tid] += sq;
    }
    __syncthreads();
    float sub[8], sc[8], bv[8];
    #pragma unroll
    for (int i = 0; i < 8; i++) {
        int cl = ct * 8 + i, d = d0 + i;
        int dc = (d < dout) ? d : (dout - 1);    // clamp param reads at padded tail
        float msv = ms[dc];
        float mean = Ls[0][cl] * inv;
        float q2   = Lq[0][cl] * inv;
        float var  = fmaxf(q2 - (2.f * msv - msv * msv) * mean * mean, 0.f);
        sub[i] = msv * mean;
        sc[i]  = gam[dc] * rsqrtf(var + EPS_GN);
        bv[i]  = bet[dc];
    }
    float ps[8], pm[8];
    #pragma unroll
    for (int i = 0; i < 8; i++) { ps[i] = 0.f; pm[i] = -INFINITY; }
    for (int r = st + rg; r < en; r += 16) {
        uint4 u = *(const uint4*)(h + (size_t)r * ld + d0);
        u32 ua[4] = {u.x, u.y, u.z, u.w};
        #pragma unroll
        for (int j = 0; j < 4; j++) {
            float o0 = (h2f((u16)(ua[j] & 0xffffu)) - sub[2 * j]) * sc[2 * j] + bv[2 * j];
            float o1 = (h2f((u16)(ua[j] >> 16)) - sub[2 * j + 1]) * sc[2 * j + 1] + bv[2 * j + 1];
            ps[2 * j] += o0; ps[2 * j + 1] += o1;
            pm[2 * j] = fmaxf(pm[2 * j], o0); pm[2 * j + 1] = fmaxf(pm[2 * j + 1], o1);
        }
    }
    __syncthreads();
    #pragma unroll
    for (int i = 0; i < 8; i++) { Ls[rg][ct * 8 + i] = ps[i]; Lq[rg][ct * 8 + i] = pm[i]; }
    __syncthreads();
    if (tid < 128) {
        float ss = 0.f, mm = -INFINITY;
        #pragma unroll
        for (int r2 = 0; r2 < 16; r2++) { ss += Ls[r2][tid]; mm = fmaxf(mm, Lq[r2][tid]); }
        int d = c0 + tid;
        if (d < dout) {
            out[(size_t)g * 2 * dout + d] = ss * inv;
            out[(size_t)g * 2 * dout + dout + d] = mm;
        }
    }
}

// ---------------- launch ----------------

extern "C" void kernel_launch(void* const* d_in, const int* in_sizes, int n_in,
                              void* d_out, int out_size, void* d_ws, size_t ws_size,
                              hipStream_t stream) {
    const float* x = (const float*)d_in[0];
    const int* ei = (const int*)d_in[1];
    const int* batch = (const int*)d_in[2];
    const float *Wl[4], *Asr[4], *Ads[4], *Bi[4], *Ga[4], *Be[4], *Ms[4];
    for (int l = 0; l < 4; l++) {
        int b = 3 + 7 * l;
        Wl[l]  = (const float*)d_in[b];
        Asr[l] = (const float*)d_in[b + 1];
        Ads[l] = (const float*)d_in[b + 2];
        Bi[l]  = (const float*)d_in[b + 3];
        Ga[l]  = (const float*)d_in[b + 4];
        Be[l]  = (const float*)d_in[b + 5];
        Ms[l]  = (const float*)d_in[b + 6];
    }

    char* ws = (char*)d_ws;
    size_t off = 0;
    auto alloc = [&](size_t bytes) -> char* {
        char* p = ws + off;
        off += (bytes + 255) & ~(size_t)255;
        return p;
    };
    u16*   actA   = (u16*)alloc((size_t)MPAD * 512 * 2);    // normalized h (layers 0-2)
    u16*   actB   = (u16*)alloc((size_t)MPAD * 1536 * 2);   // GEMM output
    u16*   agg    = (u16*)alloc((size_t)MPAD * 512 * 2);    // aggregated pre-projection (f16)
    float* agg0   = (float*)alloc((size_t)NN * 9 * 4);      // layer-0 aggregated (f32)
    u16*   WbTall = (u16*)alloc((size_t)(256 * 128 + 512 * 256 + 1536 * 512) * 2);
    float* wsrcA  = (float*)alloc((size_t)4 * 512 * 4);
    float* wdstA  = (float*)alloc((size_t)4 * 512 * 4);
    float* s_src  = (float*)alloc((size_t)NN * 4);
    float* s_dst  = (float*)alloc((size_t)NN * 4);
    float* alpha  = (float*)alloc((size_t)ET * 4);
    int* row_ptr  = (int*)alloc((size_t)(NN + 1) * 4);
    int* cursor   = (int*)alloc((size_t)NN * 4);
    int* colA     = (int*)alloc((size_t)ET * 4);
    int* counts   = (int*)alloc((size_t)NG * 4);
    int* gstart   = (int*)alloc((size_t)(NG + 1) * 4);
    int* bsum     = (int*)alloc((size_t)NBLK * 4);
    int* boff     = (int*)alloc((size_t)NBLK * 4);

    // --- zero region: deg only ---
    char* zbase = ws + off;
    int* deg      = (int*)alloc((size_t)NN * 4);
    size_t zbytes = (size_t)((ws + off) - zbase);
    hipMemsetAsync(zbase, 0, zbytes, stream);

    k_bounds<<<1, 64, 0, stream>>>(batch, counts, gstart);
    k_deg<<<(ET + 255) / 256, 256, 0, stream>>>(ei, deg);
    k_scan1<<<NBLK, 256, 0, stream>>>(deg, bsum);
    k_scan2<<<1, 256, 0, stream>>>(bsum, boff, row_ptr + NN);
    k_scan3<<<NBLK, 256, 0, stream>>>(deg, boff, row_ptr, cursor);
    k_scatter<<<(ET + 255) / 256, 256, 0, stream>>>(ei, cursor, colA);

    Ptr4 Wp{Wl[0], Wl[1], Wl[2], Wl[3]};
    Ptr4 Ap{Asr[0], Asr[1], Asr[2], Asr[3]};
    Ptr4 Dp{Ads[0], Ads[1], Ads[2], Ads[3]};
    k_wvec_all<<<dim3(512, 4), 256, 0, stream>>>(Wp, Ap, Dp, wsrcA, wdstA);
    k_wbt_all<<<dim3(48, 16, 3), 256, 0, stream>>>(Wp, WbTall);

    const int dims[5] = {9, 128, 256, 512, 1534};
    const size_t wbtOffs[3] = {0, 256 * 128, 256 * 128 + 512 * 256};
    const int RT256 = (MPAD + 255) / 256;   // 79 row tiles for the 256 GEMM
    const int NBN = (NN + 15) / 16;         // 1250 node-blocks for chunked gather

    for (int l = 0; l < 4; l++) {
        int din = dims[l], dout = dims[l + 1];
        int ldo = (dout == 1534) ? 1536 : dout;
        const float* wsrc = wsrcA + l * 512;
        const float* wdst = wdstA + l * 512;

        if (l == 0) {
            k_scores0<<<(NN + 255) / 256, 256, 0, stream>>>(x, wsrc, wdst, s_src, s_dst);
            k_agg0_fused<<<(NN + 3) / 4, 256, 0, stream>>>(x, row_ptr, colA, s_src, s_dst, agg0);
            k_gemm0<<<(NN + 1) / 2, 256, 0, stream>>>(agg0, Wl[0], Bi[0], actB);
        } else {
            if (din == 128)
                k_scores_h<2><<<(NN + 3) / 4, 256, 0, stream>>>(actA, wsrc, wdst, s_src, s_dst, din);
            else if (din == 256)
                k_scores_h<4><<<(NN + 3) / 4, 256, 0, stream>>>(actA, wsrc, wdst, s_src, s_dst, din);
            else
                k_scores_h<8><<<(NN + 3) / 4, 256, 0, stream>>>(actA, wsrc, wdst, s_src, s_dst, din);
            k_alpha<<<(NN + 3) / 4, 256, 0, stream>>>(row_ptr, colA, s_src, s_dst, alpha);
            int nchunks = din / 64;
            k_agg_gather<<<nchunks * NBN, 256, 0, stream>>>(actA, row_ptr, colA, alpha,
                                                            agg, din, NBN);
            if (l == 1) {
                int ntx = ldo / 128;
                int nwg = ntx * (MPAD / 128);
                k_gemm_f16<<<nwg, 256, 0, stream>>>(agg, WbTall + wbtOffs[0], Bi[1], actB,
                                                    din, ldo, dout, ntx);
            } else {
                int ntx = ldo / 256;            // 2 (l=2) or 6 (l=3)
                int nwg = ntx * RT256;          // 158 or 474
                k_gemm256<<<nwg, 1024, 0, stream>>>(agg, WbTall + wbtOffs[l - 1], Bi[l], actB,
                                                    din, ldo, dout, ntx, MPAD);
            }
        }

        if (l < 3)
            k_gn_fused<<<dim3(NG, ldo / 128), 256, 0, stream>>>(actB, gstart,
                                                                Ms[l], Ga[l], Be[l], actA, ldo);
        else
            k_gn_poolf<<<dim3(NG, 12), 256, 0, stream>>>(actB, gstart,
                                                         Ms[3], Ga[3], Be[3], (float*)d_out,
                                                         1534, 1536);
    }
}

// Round 9
// 327.094 us; speedup vs baseline: 1.0511x; 1.0511x over previous
//
#include <hip/hip_runtime.h>
#include <math.h>

typedef unsigned int u32;
typedef unsigned short u16;
using half8 = __attribute__((ext_vector_type(8))) _Float16;
using f32x4 = __attribute__((ext_vector_type(4))) float;

#define NN 20000
#define MPAD 20096          // 157 * 128
#define NE 160000
#define ET 180000           // NE + NN self loops
#define NG 64
#define NBLK 79             // ceil(NN/256)

constexpr float NEG_ATT = 0.2f;
constexpr float NEG_ACT = 0.01f;
constexpr float EPS_GN  = 1e-5f;

struct Ptr4 { const float *p0, *p1, *p2, *p3; };

// ---------- helpers ----------

__device__ __forceinline__ u16 f2h(float f) {
    _Float16 h = (_Float16)f;
    return __builtin_bit_cast(u16, h);
}
__device__ __forceinline__ float h2f(u16 b) {
    return (float)__builtin_bit_cast(_Float16, b);
}

__device__ __forceinline__ void gl_lds16(const void* g, void* l) {
    __builtin_amdgcn_global_load_lds((const __attribute__((address_space(1))) u32*)g,
                                     (__attribute__((address_space(3))) u32*)l, 16, 0, 0);
}

__device__ __forceinline__ float lrelu_att(float v) {
    return (v > 0.f) ? v : NEG_ATT * v;
}

// ---------------- graph bounds via binary search (batch is sorted) ----------------

__global__ void k_bounds(const int* __restrict__ batch, int* __restrict__ counts,
                         int* __restrict__ gstart) {
    __shared__ int ls[NG + 1];
    int g = threadIdx.x;           // 64 threads
    int lo = 0, hi = NN;
    while (lo < hi) {
        int mid = (lo + hi) >> 1;
        if (batch[mid] < g) lo = mid + 1; else hi = mid;
    }
    ls[g] = lo;
    if (g == 0) ls[NG] = NN;
    __syncthreads();
    counts[g] = ls[g + 1] - ls[g];
    gstart[g] = ls[g];
    if (g == 0) gstart[NG] = NN;
}

// ---------------- CSR build ----------------

__global__ void k_deg(const int* __restrict__ ei, int* deg) {
    int i = blockIdx.x * 256 + threadIdx.x;
    if (i >= ET) return;
    int dst = (i < NE) ? ei[NE + i] : (i - NE);
    atomicAdd(&deg[dst], 1);
}

__global__ void k_scan1(const int* __restrict__ deg, int* __restrict__ bsum) {
    int i = blockIdx.x * 256 + threadIdx.x;
    int v = (i < NN) ? deg[i] : 0;
    int lane = threadIdx.x & 63, w = threadIdx.x >> 6;
    #pragma unroll
    for (int off = 32; off; off >>= 1) v += __shfl_down(v, off, 64);
    __shared__ int ws[4];
    if (lane == 0) ws[w] = v;
    __syncthreads();
    if (threadIdx.x == 0) bsum[blockIdx.x] = ws[0] + ws[1] + ws[2] + ws[3];
}

__global__ void k_scan2(const int* __restrict__ bsum, int* __restrict__ boff,
                        int* __restrict__ total) {
    int tid = threadIdx.x;      // 256
    int v = (tid < NBLK) ? bsum[tid] : 0;
    int lane = tid & 63, w = tid >> 6;
    int val = v;
    #pragma unroll
    for (int off = 1; off < 64; off <<= 1) {
        int t = __shfl_up(val, off, 64);
        if (lane >= off) val += t;
    }
    __shared__ int ws[4];
    if (lane == 63) ws[w] = val;
    __syncthreads();
    int woff = 0;
    for (int k = 0; k < w; k++) woff += ws[k];
    int excl = woff + val - v;
    if (tid < NBLK) boff[tid] = excl;
    if (tid == NBLK - 1) *total = excl + v;
}

__global__ void k_scan3(const int* __restrict__ deg, const int* __restrict__ boff,
                        int* __restrict__ row_ptr, int* __restrict__ cursor) {
    int i = blockIdx.x * 256 + threadIdx.x;
    int v = (i < NN) ? deg[i] : 0;
    int lane = threadIdx.x & 63, w = threadIdx.x >> 6;
    int val = v;
    #pragma unroll
    for (int off = 1; off < 64; off <<= 1) {
        int t = __shfl_up(val, off, 64);
        if (lane >= off) val += t;
    }
    __shared__ int ws[4];
    if (lane == 63) ws[w] = val;
    __syncthreads();
    int woff = 0;
    for (int k = 0; k < w; k++) woff += ws[k];
    int excl = boff[blockIdx.x] + woff + val - v;
    if (i < NN) { row_ptr[i] = excl; cursor[i] = excl; }
}

__global__ void k_scatter(const int* __restrict__ ei, int* cursor, int* __restrict__ col) {
    int i = blockIdx.x * 256 + threadIdx.x;
    if (i >= ET) return;
    int s, d;
    if (i < NE) { s = ei[i]; d = ei[NE + i]; } else { s = i - NE; d = s; }
    int p = atomicAdd(&cursor[d], 1);
    col[p] = s;
}

// ---------------- all-layer wsrc = W @ asrc, wdst = W @ adst ----------------

__global__ void k_wvec_all(Ptr4 W, Ptr4 As, Ptr4 Ad,
                           float* __restrict__ wsrcA, float* __restrict__ wdstA) {
    const int dins[4]  = {9, 128, 256, 512};
    const int douts[4] = {128, 256, 512, 1534};
    int l = blockIdx.y, k = blockIdx.x;
    if (k >= dins[l]) return;
    const float* Wp = (l == 0) ? W.p0 : (l == 1) ? W.p1 : (l == 2) ? W.p2 : W.p3;
    const float* as = (l == 0) ? As.p0 : (l == 1) ? As.p1 : (l == 2) ? As.p2 : As.p3;
    const float* ad = (l == 0) ? Ad.p0 : (l == 1) ? Ad.p1 : (l == 2) ? Ad.p2 : Ad.p3;
    int NC = douts[l];
    const float* row = Wp + (size_t)k * NC;
    float ss = 0.f, sd = 0.f;
    for (int n = threadIdx.x; n < NC; n += 256) {
        float w = row[n];
        ss += w * as[n];
        sd += w * ad[n];
    }
    __shared__ float ls[8];
    int lane = threadIdx.x & 63, w4 = threadIdx.x >> 6;
    #pragma unroll
    for (int off = 32; off; off >>= 1) {
        ss += __shfl_down(ss, off, 64);
        sd += __shfl_down(sd, off, 64);
    }
    if (lane == 0) { ls[w4] = ss; ls[4 + w4] = sd; }
    __syncthreads();
    if (threadIdx.x == 0) {
        wsrcA[l * 512 + k] = ls[0] + ls[1] + ls[2] + ls[3];
        wdstA[l * 512 + k] = ls[4] + ls[5] + ls[6] + ls[7];
    }
}

// ---------------- all-layer W transpose + pad + f16 ----------------

__global__ void k_wbt_all(Ptr4 W, u16* __restrict__ WbTall) {
    const int Ks[3] = {128, 256, 512};
    const int NCs[3] = {256, 512, 1534};
    const int Nps[3] = {256, 512, 1536};
    const size_t offs[3] = {0, 256 * 128, 256 * 128 + 512 * 256};
    int l = blockIdx.z;
    int K = Ks[l], NC = NCs[l], Np = Nps[l];
    int n0 = blockIdx.x * 32, k0 = blockIdx.y * 32;
    if (n0 >= Np || k0 >= K) return;
    const float* Wp = (l == 0) ? W.p1 : (l == 1) ? W.p2 : W.p3;
    u16* WbT = WbTall + offs[l];
    __shared__ u16 tile[32][33];
    int tx = threadIdx.x & 31, ty = threadIdx.x >> 5;   // ty 0..7
    #pragma unroll
    for (int i = 0; i < 4; i++) {
        int k = k0 + ty + i * 8, n = n0 + tx;
        float v = (k < K && n < NC) ? Wp[(size_t)k * NC + n] : 0.f;
        tile[ty + i * 8][tx] = f2h(v);
    }
    __syncthreads();
    #pragma unroll
    for (int i = 0; i < 4; i++) {
        int n = n0 + ty + i * 8, k = k0 + tx;
        if (n < Np && k < K) WbT[(size_t)n * K + k] = tile[tx][ty + i * 8];
    }
}

// ---------------- scores ----------------

__global__ void k_scores0(const float* __restrict__ x, const float* __restrict__ wsrc,
                          const float* __restrict__ wdst, float* __restrict__ s_src,
                          float* __restrict__ s_dst) {
    int v = blockIdx.x * 256 + threadIdx.x;
    if (v >= NN) return;
    const float* r = x + (size_t)v * 9;
    float ss = 0.f, sd = 0.f;
    #pragma unroll
    for (int k = 0; k < 9; k++) { ss += r[k] * wsrc[k]; sd += r[k] * wdst[k]; }
    s_src[v] = ss; s_dst[v] = sd;
}

// VW = f16 cols per lane per load: 2 (u32), 4 (uint2), 8 (uint4)
template <int VW>
__global__ void k_scores_h(const u16* __restrict__ h, const float* __restrict__ wsrc,
                           const float* __restrict__ wdst, float* __restrict__ s_src,
                           float* __restrict__ s_dst, int din) {
    int v = blockIdx.x * 4 + (threadIdx.x >> 6);
    int lane = threadIdx.x & 63;
    if (v >= NN) return;
    const u16* row = h + (size_t)v * din;
    float ss = 0.f, sd = 0.f;
    for (int d = lane * VW; d < din; d += 64 * VW) {
        u32 ua[VW / 2];
        if constexpr (VW == 2) {
            ua[0] = *(const u32*)(row + d);
        } else if constexpr (VW == 4) {
            uint2 t = *(const uint2*)(row + d);
            ua[0] = t.x; ua[1] = t.y;
        } else {
            uint4 t = *(const uint4*)(row + d);
            ua[0] = t.x; ua[1] = t.y; ua[2] = t.z; ua[3] = t.w;
        }
        #pragma unroll
        for (int j = 0; j < VW / 2; j++) {
            float h0 = h2f((u16)(ua[j] & 0xffffu)), h1 = h2f((u16)(ua[j] >> 16));
            ss += h0 * wsrc[d + 2 * j] + h1 * wsrc[d + 2 * j + 1];
            sd += h0 * wdst[d + 2 * j] + h1 * wdst[d + 2 * j + 1];
        }
    }
    #pragma unroll
    for (int off = 32; off; off >>= 1) {
        ss += __shfl_down(ss, off, 64);
        sd += __shfl_down(sd, off, 64);
    }
    if (lane == 0) { s_src[v] = ss; s_dst[v] = sd; }
}

// ---------------- edge softmax: alpha per edge (one wave per node) ----------------
// Removes the per-edge exp/lrelu/score-gather from the wide gather kernel, where ALL
// TPN lanes of a node-group recomputed it redundantly (R7: 45% VALUBusy).

__global__ __launch_bounds__(256) void k_alpha(const int* __restrict__ row_ptr,
                                               const int* __restrict__ col,
                                               const float* __restrict__ s_src,
                                               const float* __restrict__ s_dst,
                                               float* __restrict__ alpha) {
    int grp = threadIdx.x >> 6;
    int lane = threadIdx.x & 63;
    int v = blockIdx.x * 4 + grp;
    if (v >= NN) return;
    int st = row_ptr[v], en = row_ptr[v + 1];
    float sd = s_dst[v];
    float mx = -INFINITY;
    for (int p = st + lane; p < en; p += 64)
        mx = fmaxf(mx, lrelu_att(s_src[col[p]] + sd));
    #pragma unroll
    for (int off = 32; off; off >>= 1) mx = fmaxf(mx, __shfl_xor(mx, off, 64));
    float sum = 0.f;
    for (int p = st + lane; p < en; p += 64)
        sum += __expf(lrelu_att(s_src[col[p]] + sd) - mx);
    #pragma unroll
    for (int off = 32; off; off >>= 1) sum += __shfl_xor(sum, off, 64);
    float inv = 1.0f / (sum + 1e-16f);
    for (int p = st + lane; p < en; p += 64)
        alpha[p] = __expf(lrelu_att(s_src[col[p]] + sd) - mx) * inv;
}

// ---------------- monolithic gather: agg[v] = sum_e alpha_e * h[col_e] ----------------
// R8 post-mortem: chunk-major split regressed (col/alpha re-read per chunk + 8x blocks);
// monolithic per-node layout restored. alpha precomputed; 4-edge unroll for MLP
// (deg ~9, dependent-miss chain is the latency floor; 4 loads in flight).

template <int TPN, int CPT>
__global__ __launch_bounds__(256) void k_agg2(const u16* __restrict__ h,
                                              const int* __restrict__ row_ptr,
                                              const int* __restrict__ col,
                                              const float* __restrict__ alpha,
                                              u16* __restrict__ agg, int din) {
    constexpr int NPB = 256 / TPN;
    int grp = threadIdx.x / TPN;
    int lane = threadIdx.x % TPN;
    int v = blockIdx.x * NPB + grp;
    if (v >= NN) return;
    int st = row_ptr[v], en = row_ptr[v + 1];
    int d0 = lane * 2 * CPT;
    const u16* hb = h + d0;
    float acc[2 * CPT];
    #pragma unroll
    for (int i = 0; i < 2 * CPT; i++) acc[i] = 0.f;

    auto fma1 = [&](int c, float a) {
        if constexpr (CPT == 1) {
            u32 t = *(const u32*)(hb + (size_t)c * din);
            acc[0] += a * h2f((u16)(t & 0xffffu));
            acc[1] += a * h2f((u16)(t >> 16));
        } else {
            uint2 t = *(const uint2*)(hb + (size_t)c * din);
            acc[0] += a * h2f((u16)(t.x & 0xffffu));
            acc[1] += a * h2f((u16)(t.x >> 16));
            acc[2] += a * h2f((u16)(t.y & 0xffffu));
            acc[3] += a * h2f((u16)(t.y >> 16));
        }
    };

    int p = st;
    for (; p + 4 <= en; p += 4) {
        int c0 = col[p], c1 = col[p + 1], c2 = col[p + 2], c3 = col[p + 3];
        float a0 = alpha[p], a1 = alpha[p + 1], a2 = alpha[p + 2], a3 = alpha[p + 3];
        if constexpr (CPT == 1) {
            u32 t0 = *(const u32*)(hb + (size_t)c0 * din);
            u32 t1 = *(const u32*)(hb + (size_t)c1 * din);
            u32 t2 = *(const u32*)(hb + (size_t)c2 * din);
            u32 t3 = *(const u32*)(hb + (size_t)c3 * din);
            acc[0] += a0 * h2f((u16)(t0 & 0xffffu)) + a1 * h2f((u16)(t1 & 0xffffu))
                    + a2 * h2f((u16)(t2 & 0xffffu)) + a3 * h2f((u16)(t3 & 0xffffu));
            acc[1] += a0 * h2f((u16)(t0 >> 16)) + a1 * h2f((u16)(t1 >> 16))
                    + a2 * h2f((u16)(t2 >> 16)) + a3 * h2f((u16)(t3 >> 16));
        } else {
            uint2 t0 = *(const uint2*)(hb + (size_t)c0 * din);
            uint2 t1 = *(const uint2*)(hb + (size_t)c1 * din);
            uint2 t2 = *(const uint2*)(hb + (size_t)c2 * din);
            uint2 t3 = *(const uint2*)(hb + (size_t)c3 * din);
            acc[0] += a0 * h2f((u16)(t0.x & 0xffffu)) + a1 * h2f((u16)(t1.x & 0xffffu))
                    + a2 * h2f((u16)(t2.x & 0xffffu)) + a3 * h2f((u16)(t3.x & 0xffffu));
            acc[1] += a0 * h2f((u16)(t0.x >> 16)) + a1 * h2f((u16)(t1.x >> 16))
                    + a2 * h2f((u16)(t2.x >> 16)) + a3 * h2f((u16)(t3.x >> 16));
            acc[2] += a0 * h2f((u16)(t0.y & 0xffffu)) + a1 * h2f((u16)(t1.y & 0xffffu))
                    + a2 * h2f((u16)(t2.y & 0xffffu)) + a3 * h2f((u16)(t3.y & 0xffffu));
            acc[3] += a0 * h2f((u16)(t0.y >> 16)) + a1 * h2f((u16)(t1.y >> 16))
                    + a2 * h2f((u16)(t2.y >> 16)) + a3 * h2f((u16)(t3.y >> 16));
        }
    }
    for (; p < en; p++) fma1(col[p], alpha[p]);

    if constexpr (CPT == 1) {
        u32 o = (u32)f2h(acc[0]) | ((u32)f2h(acc[1]) << 16);
        *(u32*)(agg + (size_t)v * din + d0) = o;
    } else {
        uint2 ov;
        ov.x = (u32)f2h(acc[0]) | ((u32)f2h(acc[1]) << 16);
        ov.y = (u32)f2h(acc[2]) | ((u32)f2h(acc[3]) << 16);
        *(uint2*)(agg + (size_t)v * din + d0) = ov;
    }
}

// layer-0 variant: din=9, f32 input; one wave per node, lanes 0..8 gather.
__global__ __launch_bounds__(256) void k_agg0_fused(const float* __restrict__ x,
                                                    const int* __restrict__ row_ptr,
                                                    const int* __restrict__ col,
                                                    const float* __restrict__ s_src,
                                                    const float* __restrict__ s_dst,
                                                    float* __restrict__ agg0) {
    __shared__ float sm[4 * 2];
    int grp = threadIdx.x >> 6;
    int lane = threadIdx.x & 63;
    int v = blockIdx.x * 4 + grp;
    bool valid = v < NN;
    int st = 0, en = 0;
    float sd = 0.f;
    if (valid) { st = row_ptr[v]; en = row_ptr[v + 1]; sd = s_dst[v]; }
    float mx = -INFINITY;
    if (valid) {
        for (int p = st + lane; p < en; p += 64)
            mx = fmaxf(mx, lrelu_att(s_src[col[p]] + sd));
    }
    #pragma unroll
    for (int off = 32; off; off >>= 1) mx = fmaxf(mx, __shfl_xor(mx, off, 64));
    float sum = 0.f;
    if (valid) {
        for (int p = st + lane; p < en; p += 64)
            sum += __expf(lrelu_att(s_src[col[p]] + sd) - mx);
    }
    #pragma unroll
    for (int off = 32; off; off >>= 1) sum += __shfl_xor(sum, off, 64);
    if (lane == 0) { sm[grp * 2] = mx; sm[grp * 2 + 1] = 1.0f / (sum + 1e-16f); }
    __syncthreads();
    if (!valid || lane >= 9) return;
    float m = sm[grp * 2], inv = sm[grp * 2 + 1];
    float acc = 0.f;
    for (int p = st; p < en; p++) {
        int c = col[p];
        float a = __expf(lrelu_att(s_src[c] + sd) - m);
        acc += a * x[(size_t)c * 9 + lane];
    }
    agg0[(size_t)v * 9 + lane] = acc * inv;
}

// ---------------- layer 0 GEMM: agg0[NN][9] f32 @ W0[9][128] + bias + lrelu ----------------

__global__ __launch_bounds__(256) void k_gemm0(const float* __restrict__ agg0,
                                               const float* __restrict__ W,
                                               const float* __restrict__ bias,
                                               u16* __restrict__ out) {
    __shared__ float Ws[9 * 128];
    for (int i = threadIdx.x; i < 9 * 128; i += 256) Ws[i] = W[i];
    __syncthreads();
    int node = blockIdx.x * 2 + (threadIdx.x >> 7);
    int n = threadIdx.x & 127;
    if (node >= NN) return;
    const float* xr = agg0 + (size_t)node * 9;
    float acc = bias[n];
    #pragma unroll
    for (int k = 0; k < 9; k++) acc += xr[k] * Ws[k * 128 + n];
    acc = (acc > 0.f) ? acc : NEG_ACT * acc;
    out[(size_t)node * 128 + n] = f2h(acc);
}

// ---------------- 128x128 MFMA GEMM (kept for layer 1) ----------------

#define BM 128
#define BK 32

__global__ __launch_bounds__(256) void k_gemm_f16(const u16* __restrict__ A,
                                                  const u16* __restrict__ B,
                                                  const float* __restrict__ bias,
                                                  u16* __restrict__ C,
                                                  int K, int ldC, int NC, int ntx) {
    int nwg = gridDim.x;
    int b = blockIdx.x;
    int q = nwg >> 3, r = nwg & 7;
    int xcd = b & 7, idx = b >> 3;
    int wg = (xcd < r ? xcd * (q + 1) : r * (q + 1) + (xcd - r) * q) + idx;
    int row0 = (wg / ntx) * BM;
    int col0 = (wg % ntx) * BM;

    __shared__ u16 lds[2][2][BM * BK];   // 32 KiB
    int tid = threadIdx.x;
    int lane = tid & 63, w = tid >> 6;
    int wr = w >> 1, wc = w & 1;

    f32x4 acc[4][4];
    #pragma unroll
    for (int m = 0; m < 4; m++)
        #pragma unroll
        for (int n = 0; n < 4; n++)
            #pragma unroll
            for (int rr2 = 0; rr2 < 4; rr2++) acc[m][n][rr2] = 0.f;

    int nt = K / BK;

    auto stage = [&](int buf, int t) {
        int k0 = t * BK;
        #pragma unroll
        for (int c = 0; c < 2; c++) {
            int idx2 = tid + c * 256;           // 0..511
            int rr2 = idx2 >> 2, kc = idx2 & 3;
            int kcs = kc ^ (rr2 & 3);           // pre-swizzled global source
            gl_lds16(A + (size_t)(row0 + rr2) * K + k0 + kcs * 8, &lds[buf][0][idx2 * 8]);
            gl_lds16(B + (size_t)(col0 + rr2) * K + k0 + kcs * 8, &lds[buf][1][idx2 * 8]);
        }
    };

    auto compute = [&](int buf) {
        const u16* As = &lds[buf][0][0];
        const u16* Bs = &lds[buf][1][0];
        int kg = lane >> 4, rl = lane & 15;
        half8 af[4], bfr[4];
        #pragma unroll
        for (int m = 0; m < 4; m++) {
            int rr2 = wr * 64 + m * 16 + rl;
            af[m] = *(const half8*)(As + rr2 * BK + (kg ^ (rr2 & 3)) * 8);
        }
        #pragma unroll
        for (int n = 0; n < 4; n++) {
            int rr2 = wc * 64 + n * 16 + rl;
            bfr[n] = *(const half8*)(Bs + rr2 * BK + (kg ^ (rr2 & 3)) * 8);
        }
        #pragma unroll
        for (int m = 0; m < 4; m++)
            #pragma unroll
            for (int n = 0; n < 4; n++)
                acc[m][n] = __builtin_amdgcn_mfma_f32_16x16x32_f16(af[m], bfr[n], acc[m][n], 0, 0, 0);
    };

    stage(0, 0);
    __syncthreads();
    for (int t = 0; t < nt; t++) {
        if (t + 1 < nt) stage((t + 1) & 1, t + 1);
        compute(t & 1);
        __syncthreads();
    }

    u16* ep = ((u16*)lds) + w * (32 * 72);
    int kg = lane >> 4, rl = lane & 15;
    int rrow = lane >> 3;
    int c8 = (lane & 7) * 8;
    #pragma unroll
    for (int half = 0; half < 2; half++) {
        #pragma unroll
        for (int m2 = 0; m2 < 2; m2++) {
            int m = half * 2 + m2;
            #pragma unroll
            for (int n = 0; n < 4; n++) {
                int colg = col0 + wc * 64 + n * 16 + rl;
                float bb = (colg < NC) ? bias[colg] : 0.f;
                #pragma unroll
                for (int rr2 = 0; rr2 < 4; rr2++) {
                    float o = acc[m][n][rr2] + bb;
                    o = (o > 0.f) ? o : NEG_ACT * o;
                    ep[(m2 * 16 + kg * 4 + rr2) * 72 + n * 16 + rl] = f2h(o);
                }
            }
        }
        #pragma unroll
        for (int it = 0; it < 4; it++) {
            int rloc = it * 8 + rrow;
            half8 vv = *(const half8*)(ep + rloc * 72 + c8);
            int rowg = row0 + wr * 64 + half * 32 + rloc;
            *(half8*)(C + (size_t)rowg * ldC + col0 + wc * 64 + c8) = vv;
        }
    }
}

// ---------------- 256x256 MFMA GEMM: BK=32, TRIPLE buffer, ONE barrier/K-tile ----------------

__global__ __launch_bounds__(1024, 4) void k_gemm256(const u16* __restrict__ A,
                                                     const u16* __restrict__ B,
                                                     const float* __restrict__ bias,
                                                     u16* __restrict__ C,
                                                     int K, int ldC, int NC, int ntx, int M) {
    __shared__ u16 sMem[49152];   // 3 bufs x (A 8192 + B 8192) u16 = 96 KiB

    int nwg = gridDim.x, b = blockIdx.x;
    int q = nwg >> 3, r = nwg & 7;
    int xcd = b & 7, bidx = b >> 3;
    int wg = (xcd < r ? xcd * (q + 1) : r * (q + 1) + (xcd - r) * q) + bidx;
    int row0 = (wg / ntx) * 256;
    int col0 = (wg % ntx) * 256;

    int tid = threadIdx.x;
    int w = tid >> 6, lane = tid & 63;
    int wm = w >> 2, wn = w & 3;           // 4 x 4 wave grid, 64x64 out per wave
    int rl = lane & 15, kg = lane >> 4;
    int ksl = (kg ^ ((rl >> 1) & 3)) * 8;  // swizzled read slot offset (u16 units)

    f32x4 acc[4][4];
    #pragma unroll
    for (int m = 0; m < 4; m++)
        #pragma unroll
        for (int n = 0; n < 4; n++)
            #pragma unroll
            for (int i = 0; i < 4; i++) acc[m][n][i] = 0.f;

    {
        int rr = tid >> 2, s = tid & 3;
        int ss = s ^ ((rr >> 1) & 3);
        int ra = row0 + rr; ra = (ra < M) ? ra : (M - 1);
        const u16* aSrc0 = A + (size_t)ra * K + ss * 8;
        const u16* bSrc0 = B + (size_t)(col0 + rr) * K + ss * 8;
        u16* dstA = sMem + tid * 8;
        u16* dstB = sMem + 8192 + tid * 8;

        auto stage = [&](int t, int bf2) {
            gl_lds16(aSrc0 + t * 32, dstA + bf2 * 16384);
            gl_lds16(bSrc0 + t * 32, dstB + bf2 * 16384);
        };

        half8 af[4], bf[4];
        auto ldAB = [&](int bf2) {
            const u16* Ab = sMem + bf2 * 16384;
            const u16* Bb = Ab + 8192;
            #pragma unroll
            for (int i = 0; i < 4; i++)
                af[i] = *(const half8*)(Ab + (wm * 64 + i * 16 + rl) * 32 + ksl);
            #pragma unroll
            for (int i = 0; i < 4; i++)
                bf[i] = *(const half8*)(Bb + (wn * 64 + i * 16 + rl) * 32 + ksl);
        };

        int nt = K >> 5;    // K-tiles of 32; nt >= 8 for our shapes

        stage(0, 0); stage(1, 1);
        __builtin_amdgcn_sched_barrier(0);
        asm volatile("s_waitcnt vmcnt(2)" ::: "memory");
        __builtin_amdgcn_s_barrier();
        __builtin_amdgcn_sched_barrier(0);

        int rb = 0;
        for (int t = 0; t < nt; t++) {
            int sb = rb + 2; if (sb >= 3) sb -= 3;
            if (t + 2 < nt) stage(t + 2, sb);
            ldAB(rb);
            __builtin_amdgcn_s_setprio(1);
            #pragma unroll
            for (int i = 0; i < 4; i++)
                #pragma unroll
                for (int n = 0; n < 4; n++)
                    acc[i][n] = __builtin_amdgcn_mfma_f32_16x16x32_f16(af[i], bf[n], acc[i][n], 0, 0, 0);
            __builtin_amdgcn_s_setprio(0);
            __builtin_amdgcn_sched_barrier(0);
            if (t + 2 < nt)      asm volatile("s_waitcnt vmcnt(2)" ::: "memory");
            else if (t + 1 < nt) asm volatile("s_waitcnt vmcnt(0)" ::: "memory");
            __builtin_amdgcn_s_barrier();
            __builtin_amdgcn_sched_barrier(0);
            rb = (rb == 2) ? 0 : rb + 1;
        }
    }

    // epilogue: per-wave private 32x72 LDS staging region, coalesced half8 stores
    u16* ep = sMem + w * (32 * 72);
    float bv[4];
    #pragma unroll
    for (int n = 0; n < 4; n++) {
        int colg = col0 + wn * 64 + n * 16 + rl;
        bv[n] = (colg < NC) ? bias[colg] : 0.f;
    }
    int rrow = lane >> 3, c8 = (lane & 7) * 8;
    #pragma unroll
    for (int mh = 0; mh < 2; mh++) {
        #pragma unroll
        for (int msub = 0; msub < 2; msub++) {
            int m = mh * 2 + msub;
            #pragma unroll
            for (int n = 0; n < 4; n++) {
                #pragma unroll
                for (int rg = 0; rg < 4; rg++) {
                    float o = acc[m][n][rg] + bv[n];
                    o = (o > 0.f) ? o : NEG_ACT * o;
                    ep[(msub * 16 + kg * 4 + rg) * 72 + n * 16 + rl] = f2h(o);
                }
            }
        }
        #pragma unroll
        for (int it = 0; it < 4; it++) {
            int rloc = it * 8 + rrow;
            half8 vv = *(const half8*)(ep + rloc * 72 + c8);
            int rowg = row0 + wm * 64 + mh * 32 + rloc;
            if (rowg < M)
                *(half8*)(C + (size_t)rowg * ldC + col0 + wn * 64 + c8) = vv;
        }
    }
}

// ---------------- GraphNorm fused: stats + apply (or pool) in ONE kernel ----------------

__global__ __launch_bounds__(256) void k_gn_fused(const u16* __restrict__ h,
                           const int* __restrict__ gstart,
                           const float* __restrict__ ms, const float* __restrict__ gam,
                           const float* __restrict__ bet, u16* __restrict__ out, int ld) {
    int g = blockIdx.x;
    int c0 = blockIdx.y * 128;
    int ct = threadIdx.x & 15, rg = threadIdx.x >> 4;
    int d0 = c0 + ct * 8;
    int st = gstart[g], en = gstart[g + 1];
    float inv = 1.0f / (float)(en - st);
    float s[8], qq[8];
    #pragma unroll
    for (int i = 0; i < 8; i++) { s[i] = 0.f; qq[i] = 0.f; }
    for (int r = st + rg; r < en; r += 16) {
        uint4 u = *(const uint4*)(h + (size_t)r * ld + d0);
        u32 ua[4] = {u.x, u.y, u.z, u.w};
        #pragma unroll
        for (int j = 0; j < 4; j++) {
            float v0 = h2f((u16)(ua[j] & 0xffffu)), v1 = h2f((u16)(ua[j] >> 16));
            s[2 * j] += v0; s[2 * j + 1] += v1;
            qq[2 * j] += v0 * v0; qq[2 * j + 1] += v1 * v1;
        }
    }
    __shared__ float Ls[16][128], Lq[16][128];
    #pragma unroll
    for (int i = 0; i < 8; i++) { Ls[rg][ct * 8 + i] = s[i]; Lq[rg][ct * 8 + i] = qq[i]; }
    __syncthreads();
    int tid = threadIdx.x;
    if (tid < 128) {
        float ss = 0.f, sq = 0.f;
        #pragma unroll
        for (int r2 = 1; r2 < 16; r2++) { ss += Ls[r2][tid]; sq += Lq[r2][tid]; }
        Ls[0][tid] += ss; Lq[0][tid] += sq;
    }
    __syncthreads();
    float sub[8], sc[8], bv[8];
    #pragma unroll
    for (int i = 0; i < 8; i++) {
        int cl = ct * 8 + i, d = d0 + i;
        float msv = ms[d];
        float mean = Ls[0][cl] * inv;
        float q2   = Lq[0][cl] * inv;
        float var  = fmaxf(q2 - (2.f * msv - msv * msv) * mean * mean, 0.f);
        sub[i] = msv * mean;
        sc[i]  = gam[d] * rsqrtf(var + EPS_GN);
        bv[i]  = bet[d];
    }
    for (int r = st + rg; r < en; r += 16) {
        uint4 u = *(const uint4*)(h + (size_t)r * ld + d0);
        u32 ua[4] = {u.x, u.y, u.z, u.w};
        uint4 wv4;
        u32 wo[4];
        #pragma unroll
        for (int j = 0; j < 4; j++) {
            float o0 = (h2f((u16)(ua[j] & 0xffffu)) - sub[2 * j]) * sc[2 * j] + bv[2 * j];
            float o1 = (h2f((u16)(ua[j] >> 16)) - sub[2 * j + 1]) * sc[2 * j + 1] + bv[2 * j + 1];
            wo[j] = (u32)f2h(o0) | ((u32)f2h(o1) << 16);
        }
        wv4.x = wo[0]; wv4.y = wo[1]; wv4.z = wo[2]; wv4.w = wo[3];
        *(uint4*)(out + (size_t)r * ld + d0) = wv4;
    }
}

// l=3: fused stats + normalize + mean/max pool, writing d_out directly.
__global__ __launch_bounds__(256) void k_gn_poolf(const u16* __restrict__ h,
                           const int* __restrict__ gstart,
                           const float* __restrict__ ms, const float* __restrict__ gam,
                           const float* __restrict__ bet, float* __restrict__ out,
                           int dout, int ld) {
    int g = blockIdx.x;
    int c0 = blockIdx.y * 128;
    int ct = threadIdx.x & 15, rg = threadIdx.x >> 4;
    int d0 = c0 + ct * 8;
    int st = gstart[g], en = gstart[g + 1];
    float inv = 1.0f / (float)(en - st);
    float s[8], qq[8];
    #pragma unroll
    for (int i = 0; i < 8; i++) { s[i] = 0.f; qq[i] = 0.f; }
    for (int r = st + rg; r < en; r += 16) {
        uint4 u = *(const uint4*)(h + (size_t)r * ld + d0);
        u32 ua[4] = {u.x, u.y, u.z, u.w};
        #pragma unroll
        for (int j = 0; j < 4; j++) {
            float v0 = h2f((u16)(ua[j] & 0xffffu)), v1 = h2f((u16)(ua[j] >> 16));
            s[2 * j] += v0; s[2 * j + 1] += v1;
            qq[2 * j] += v0 * v0; qq[2 * j + 1] += v1 * v1;
        }
    }
    __shared__ float Ls[16][128], Lq[16][128];
    #pragma unroll
    for (int i = 0; i < 8; i++) { Ls[rg][ct * 8 + i] = s[i]; Lq[rg][ct * 8 + i] = qq[i]; }
    __syncthreads();
    int tid = threadIdx.x;
    if (tid < 128) {
        float ss = 0.f, sq = 0.f;
        #pragma unroll
        for (int r2 = 1; r2 < 16; r2++) { ss += Ls[r2][tid]; sq += Lq[r2][tid]; }
        Ls[0][tid] += ss; Lq[0][tid] += sq;
    }
    __syncthreads();
    float sub[8], sc[8], bv[8];
    #pragma unroll
    for (int i = 0; i < 8; i++) {
        int cl = ct * 8 + i, d = d0 + i;
        int dc = (d < dout) ? d : (dout - 1);    // clamp param reads at padded tail
        float msv = ms[dc];
        float mean = Ls[0][cl] * inv;
        float q2   = Lq[0][cl] * inv;
        float var  = fmaxf(q2 - (2.f * msv - msv * msv) * mean * mean, 0.f);
        sub[i] = msv * mean;
        sc[i]  = gam[dc] * rsqrtf(var + EPS_GN);
        bv[i]  = bet[dc];
    }
    float ps[8], pm[8];
    #pragma unroll
    for (int i = 0; i < 8; i++) { ps[i] = 0.f; pm[i] = -INFINITY; }
    for (int r = st + rg; r < en; r += 16) {
        uint4 u = *(const uint4*)(h + (size_t)r * ld + d0);
        u32 ua[4] = {u.x, u.y, u.z, u.w};
        #pragma unroll
        for (int j = 0; j < 4; j++) {
            float o0 = (h2f((u16)(ua[j] & 0xffffu)) - sub[2 * j]) * sc[2 * j] + bv[2 * j];
            float o1 = (h2f((u16)(ua[j] >> 16)) - sub[2 * j + 1]) * sc[2 * j + 1] + bv[2 * j + 1];
            ps[2 * j] += o0; ps[2 * j + 1] += o1;
            pm[2 * j] = fmaxf(pm[2 * j], o0); pm[2 * j + 1] = fmaxf(pm[2 * j + 1], o1);
        }
    }
    __syncthreads();
    #pragma unroll
    for (int i = 0; i < 8; i++) { Ls[rg][ct * 8 + i] = ps[i]; Lq[rg][ct * 8 + i] = pm[i]; }
    __syncthreads();
    if (tid < 128) {
        float ss = 0.f, mm = -INFINITY;
        #pragma unroll
        for (int r2 = 0; r2 < 16; r2++) { ss += Ls[r2][tid]; mm = fmaxf(mm, Lq[r2][tid]); }
        int d = c0 + tid;
        if (d < dout) {
            out[(size_t)g * 2 * dout + d] = ss * inv;
            out[(size_t)g * 2 * dout + dout + d] = mm;
        }
    }
}

// ---------------- launch ----------------

extern "C" void kernel_launch(void* const* d_in, const int* in_sizes, int n_in,
                              void* d_out, int out_size, void* d_ws, size_t ws_size,
                              hipStream_t stream) {
    const float* x = (const float*)d_in[0];
    const int* ei = (const int*)d_in[1];
    const int* batch = (const int*)d_in[2];
    const float *Wl[4], *Asr[4], *Ads[4], *Bi[4], *Ga[4], *Be[4], *Ms[4];
    for (int l = 0; l < 4; l++) {
        int b = 3 + 7 * l;
        Wl[l]  = (const float*)d_in[b];
        Asr[l] = (const float*)d_in[b + 1];
        Ads[l] = (const float*)d_in[b + 2];
        Bi[l]  = (const float*)d_in[b + 3];
        Ga[l]  = (const float*)d_in[b + 4];
        Be[l]  = (const float*)d_in[b + 5];
        Ms[l]  = (const float*)d_in[b + 6];
    }

    char* ws = (char*)d_ws;
    size_t off = 0;
    auto alloc = [&](size_t bytes) -> char* {
        char* p = ws + off;
        off += (bytes + 255) & ~(size_t)255;
        return p;
    };
    u16*   actA   = (u16*)alloc((size_t)MPAD * 512 * 2);    // normalized h (layers 0-2)
    u16*   actB   = (u16*)alloc((size_t)MPAD * 1536 * 2);   // GEMM output
    u16*   agg    = (u16*)alloc((size_t)MPAD * 512 * 2);    // aggregated pre-projection (f16)
    float* agg0   = (float*)alloc((size_t)NN * 9 * 4);      // layer-0 aggregated (f32)
    u16*   WbTall = (u16*)alloc((size_t)(256 * 128 + 512 * 256 + 1536 * 512) * 2);
    float* wsrcA  = (float*)alloc((size_t)4 * 512 * 4);
    float* wdstA  = (float*)alloc((size_t)4 * 512 * 4);
    float* s_src  = (float*)alloc((size_t)NN * 4);
    float* s_dst  = (float*)alloc((size_t)NN * 4);
    float* alpha  = (float*)alloc((size_t)ET * 4);
    int* row_ptr  = (int*)alloc((size_t)(NN + 1) * 4);
    int* cursor   = (int*)alloc((size_t)NN * 4);
    int* colA     = (int*)alloc((size_t)ET * 4);
    int* counts   = (int*)alloc((size_t)NG * 4);
    int* gstart   = (int*)alloc((size_t)(NG + 1) * 4);
    int* bsum     = (int*)alloc((size_t)NBLK * 4);
    int* boff     = (int*)alloc((size_t)NBLK * 4);

    // --- zero region: deg only ---
    char* zbase = ws + off;
    int* deg      = (int*)alloc((size_t)NN * 4);
    size_t zbytes = (size_t)((ws + off) - zbase);
    hipMemsetAsync(zbase, 0, zbytes, stream);

    k_bounds<<<1, 64, 0, stream>>>(batch, counts, gstart);
    k_deg<<<(ET + 255) / 256, 256, 0, stream>>>(ei, deg);
    k_scan1<<<NBLK, 256, 0, stream>>>(deg, bsum);
    k_scan2<<<1, 256, 0, stream>>>(bsum, boff, row_ptr + NN);
    k_scan3<<<NBLK, 256, 0, stream>>>(deg, boff, row_ptr, cursor);
    k_scatter<<<(ET + 255) / 256, 256, 0, stream>>>(ei, cursor, colA);

    Ptr4 Wp{Wl[0], Wl[1], Wl[2], Wl[3]};
    Ptr4 Ap{Asr[0], Asr[1], Asr[2], Asr[3]};
    Ptr4 Dp{Ads[0], Ads[1], Ads[2], Ads[3]};
    k_wvec_all<<<dim3(512, 4), 256, 0, stream>>>(Wp, Ap, Dp, wsrcA, wdstA);
    k_wbt_all<<<dim3(48, 16, 3), 256, 0, stream>>>(Wp, WbTall);

    const int dims[5] = {9, 128, 256, 512, 1534};
    const size_t wbtOffs[3] = {0, 256 * 128, 256 * 128 + 512 * 256};
    const int RT256 = (MPAD + 255) / 256;   // 79 row tiles for the 256 GEMM

    for (int l = 0; l < 4; l++) {
        int din = dims[l], dout = dims[l + 1];
        int ldo = (dout == 1534) ? 1536 : dout;
        const float* wsrc = wsrcA + l * 512;
        const float* wdst = wdstA + l * 512;

        if (l == 0) {
            k_scores0<<<(NN + 255) / 256, 256, 0, stream>>>(x, wsrc, wdst, s_src, s_dst);
            k_agg0_fused<<<(NN + 3) / 4, 256, 0, stream>>>(x, row_ptr, colA, s_src, s_dst, agg0);
            k_gemm0<<<(NN + 1) / 2, 256, 0, stream>>>(agg0, Wl[0], Bi[0], actB);
        } else {
            if (din == 128)
                k_scores_h<2><<<(NN + 3) / 4, 256, 0, stream>>>(actA, wsrc, wdst, s_src, s_dst, din);
            else if (din == 256)
                k_scores_h<4><<<(NN + 3) / 4, 256, 0, stream>>>(actA, wsrc, wdst, s_src, s_dst, din);
            else
                k_scores_h<8><<<(NN + 3) / 4, 256, 0, stream>>>(actA, wsrc, wdst, s_src, s_dst, din);
            k_alpha<<<(NN + 3) / 4, 256, 0, stream>>>(row_ptr, colA, s_src, s_dst, alpha);
            if (din == 128)
                k_agg2<64, 1><<<(NN + 3) / 4, 256, 0, stream>>>(actA, row_ptr, colA, alpha, agg, din);
            else if (din == 256)
                k_agg2<64, 2><<<(NN + 3) / 4, 256, 0, stream>>>(actA, row_ptr, colA, alpha, agg, din);
            else
                k_agg2<128, 2><<<(NN + 1) / 2, 256, 0, stream>>>(actA, row_ptr, colA, alpha, agg, din);
            if (l == 1) {
                int ntx = ldo / 128;
                int nwg = ntx * (MPAD / 128);
                k_gemm_f16<<<nwg, 256, 0, stream>>>(agg, WbTall + wbtOffs[0], Bi[1], actB,
                                                    din, ldo, dout, ntx);
            } else {
                int ntx = ldo / 256;            // 2 (l=2) or 6 (l=3)
                int nwg = ntx * RT256;          // 158 or 474
                k_gemm256<<<nwg, 1024, 0, stream>>>(agg, WbTall + wbtOffs[l - 1], Bi[l], actB,
                                                    din, ldo, dout, ntx, MPAD);
            }
        }

        if (l < 3)
            k_gn_fused<<<dim3(NG, ldo / 128), 256, 0, stream>>>(actB, gstart,
                                                                Ms[l], Ga[l], Be[l], actA, ldo);
        else
            k_gn_poolf<<<dim3(NG, 12), 256, 0, stream>>>(actB, gstart,
                                                         Ms[3], Ga[3], Be[3], (float*)d_out,
                                                         1534, 1536);
    }
}

// Round 10
// 308.290 us; speedup vs baseline: 1.1152x; 1.0610x over previous
//
#include <hip/hip_runtime.h>
#include <math.h>

typedef unsigned int u32;
typedef unsigned short u16;
using half8 = __attribute__((ext_vector_type(8))) _Float16;
using f32x4 = __attribute__((ext_vector_type(4))) float;

#define NN 20000
#define MPAD 20096          // 157 * 128
#define NE 160000
#define ET 180000           // NE + NN self loops
#define NG 64
#define NBLK 79             // ceil(NN/256)

constexpr float NEG_ATT = 0.2f;
constexpr float NEG_ACT = 0.01f;
constexpr float EPS_GN  = 1e-5f;

struct Ptr4 { const float *p0, *p1, *p2, *p3; };

// ---------- helpers ----------

__device__ __forceinline__ u16 f2h(float f) {
    _Float16 h = (_Float16)f;
    return __builtin_bit_cast(u16, h);
}
__device__ __forceinline__ float h2f(u16 b) {
    return (float)__builtin_bit_cast(_Float16, b);
}

__device__ __forceinline__ void gl_lds16(const void* g, void* l) {
    __builtin_amdgcn_global_load_lds((const __attribute__((address_space(1))) u32*)g,
                                     (__attribute__((address_space(3))) u32*)l, 16, 0, 0);
}

__device__ __forceinline__ float lrelu_att(float v) {
    return (v > 0.f) ? v : NEG_ATT * v;
}

// ---------------- graph bounds via binary search (batch is sorted) ----------------

__global__ void k_bounds(const int* __restrict__ batch, int* __restrict__ counts,
                         int* __restrict__ gstart) {
    __shared__ int ls[NG + 1];
    int g = threadIdx.x;           // 64 threads
    int lo = 0, hi = NN;
    while (lo < hi) {
        int mid = (lo + hi) >> 1;
        if (batch[mid] < g) lo = mid + 1; else hi = mid;
    }
    ls[g] = lo;
    if (g == 0) ls[NG] = NN;
    __syncthreads();
    counts[g] = ls[g + 1] - ls[g];
    gstart[g] = ls[g];
    if (g == 0) gstart[NG] = NN;
}

// ---------------- CSR build ----------------

__global__ void k_deg(const int* __restrict__ ei, int* deg) {
    int i = blockIdx.x * 256 + threadIdx.x;
    if (i >= ET) return;
    int dst = (i < NE) ? ei[NE + i] : (i - NE);
    atomicAdd(&deg[dst], 1);
}

__global__ void k_scan1(const int* __restrict__ deg, int* __restrict__ bsum) {
    int i = blockIdx.x * 256 + threadIdx.x;
    int v = (i < NN) ? deg[i] : 0;
    int lane = threadIdx.x & 63, w = threadIdx.x >> 6;
    #pragma unroll
    for (int off = 32; off; off >>= 1) v += __shfl_down(v, off, 64);
    __shared__ int ws[4];
    if (lane == 0) ws[w] = v;
    __syncthreads();
    if (threadIdx.x == 0) bsum[blockIdx.x] = ws[0] + ws[1] + ws[2] + ws[3];
}

__global__ void k_scan2(const int* __restrict__ bsum, int* __restrict__ boff,
                        int* __restrict__ total) {
    int tid = threadIdx.x;      // 256
    int v = (tid < NBLK) ? bsum[tid] : 0;
    int lane = tid & 63, w = tid >> 6;
    int val = v;
    #pragma unroll
    for (int off = 1; off < 64; off <<= 1) {
        int t = __shfl_up(val, off, 64);
        if (lane >= off) val += t;
    }
    __shared__ int ws[4];
    if (lane == 63) ws[w] = val;
    __syncthreads();
    int woff = 0;
    for (int k = 0; k < w; k++) woff += ws[k];
    int excl = woff + val - v;
    if (tid < NBLK) boff[tid] = excl;
    if (tid == NBLK - 1) *total = excl + v;
}

__global__ void k_scan3(const int* __restrict__ deg, const int* __restrict__ boff,
                        int* __restrict__ row_ptr, int* __restrict__ cursor) {
    int i = blockIdx.x * 256 + threadIdx.x;
    int v = (i < NN) ? deg[i] : 0;
    int lane = threadIdx.x & 63, w = threadIdx.x >> 6;
    int val = v;
    #pragma unroll
    for (int off = 1; off < 64; off <<= 1) {
        int t = __shfl_up(val, off, 64);
        if (lane >= off) val += t;
    }
    __shared__ int ws[4];
    if (lane == 63) ws[w] = val;
    __syncthreads();
    int woff = 0;
    for (int k = 0; k < w; k++) woff += ws[k];
    int excl = boff[blockIdx.x] + woff + val - v;
    if (i < NN) { row_ptr[i] = excl; cursor[i] = excl; }
}

__global__ void k_scatter(const int* __restrict__ ei, int* cursor, int* __restrict__ col) {
    int i = blockIdx.x * 256 + threadIdx.x;
    if (i >= ET) return;
    int s, d;
    if (i < NE) { s = ei[i]; d = ei[NE + i]; } else { s = i - NE; d = s; }
    int p = atomicAdd(&cursor[d], 1);
    col[p] = s;
}

// ---------------- all-layer wsrc = W @ asrc, wdst = W @ adst ----------------

__global__ void k_wvec_all(Ptr4 W, Ptr4 As, Ptr4 Ad,
                           float* __restrict__ wsrcA, float* __restrict__ wdstA) {
    const int dins[4]  = {9, 128, 256, 512};
    const int douts[4] = {128, 256, 512, 1534};
    int l = blockIdx.y, k = blockIdx.x;
    if (k >= dins[l]) return;
    const float* Wp = (l == 0) ? W.p0 : (l == 1) ? W.p1 : (l == 2) ? W.p2 : W.p3;
    const float* as = (l == 0) ? As.p0 : (l == 1) ? As.p1 : (l == 2) ? As.p2 : As.p3;
    const float* ad = (l == 0) ? Ad.p0 : (l == 1) ? Ad.p1 : (l == 2) ? Ad.p2 : Ad.p3;
    int NC = douts[l];
    const float* row = Wp + (size_t)k * NC;
    float ss = 0.f, sd = 0.f;
    for (int n = threadIdx.x; n < NC; n += 256) {
        float w = row[n];
        ss += w * as[n];
        sd += w * ad[n];
    }
    __shared__ float ls[8];
    int lane = threadIdx.x & 63, w4 = threadIdx.x >> 6;
    #pragma unroll
    for (int off = 32; off; off >>= 1) {
        ss += __shfl_down(ss, off, 64);
        sd += __shfl_down(sd, off, 64);
    }
    if (lane == 0) { ls[w4] = ss; ls[4 + w4] = sd; }
    __syncthreads();
    if (threadIdx.x == 0) {
        wsrcA[l * 512 + k] = ls[0] + ls[1] + ls[2] + ls[3];
        wdstA[l * 512 + k] = ls[4] + ls[5] + ls[6] + ls[7];
    }
}

// ---------------- all-layer W transpose + pad + f16 ----------------

__global__ void k_wbt_all(Ptr4 W, u16* __restrict__ WbTall) {
    const int Ks[3] = {128, 256, 512};
    const int NCs[3] = {256, 512, 1534};
    const int Nps[3] = {256, 512, 1536};
    const size_t offs[3] = {0, 256 * 128, 256 * 128 + 512 * 256};
    int l = blockIdx.z;
    int K = Ks[l], NC = NCs[l], Np = Nps[l];
    int n0 = blockIdx.x * 32, k0 = blockIdx.y * 32;
    if (n0 >= Np || k0 >= K) return;
    const float* Wp = (l == 0) ? W.p1 : (l == 1) ? W.p2 : W.p3;
    u16* WbT = WbTall + offs[l];
    __shared__ u16 tile[32][33];
    int tx = threadIdx.x & 31, ty = threadIdx.x >> 5;   // ty 0..7
    #pragma unroll
    for (int i = 0; i < 4; i++) {
        int k = k0 + ty + i * 8, n = n0 + tx;
        float v = (k < K && n < NC) ? Wp[(size_t)k * NC + n] : 0.f;
        tile[ty + i * 8][tx] = f2h(v);
    }
    __syncthreads();
    #pragma unroll
    for (int i = 0; i < 4; i++) {
        int n = n0 + ty + i * 8, k = k0 + tx;
        if (n < Np && k < K) WbT[(size_t)n * K + k] = tile[tx][ty + i * 8];
    }
}

// ---------------- scores ----------------

__global__ void k_scores0(const float* __restrict__ x, const float* __restrict__ wsrc,
                          const float* __restrict__ wdst, float* __restrict__ s_src,
                          float* __restrict__ s_dst) {
    int v = blockIdx.x * 256 + threadIdx.x;
    if (v >= NN) return;
    const float* r = x + (size_t)v * 9;
    float ss = 0.f, sd = 0.f;
    #pragma unroll
    for (int k = 0; k < 9; k++) { ss += r[k] * wsrc[k]; sd += r[k] * wdst[k]; }
    s_src[v] = ss; s_dst[v] = sd;
}

// VW = f16 cols per lane per load: 2 (u32), 4 (uint2), 8 (uint4)
template <int VW>
__global__ void k_scores_h(const u16* __restrict__ h, const float* __restrict__ wsrc,
                           const float* __restrict__ wdst, float* __restrict__ s_src,
                           float* __restrict__ s_dst, int din) {
    int v = blockIdx.x * 4 + (threadIdx.x >> 6);
    int lane = threadIdx.x & 63;
    if (v >= NN) return;
    const u16* row = h + (size_t)v * din;
    float ss = 0.f, sd = 0.f;
    for (int d = lane * VW; d < din; d += 64 * VW) {
        u32 ua[VW / 2];
        if constexpr (VW == 2) {
            ua[0] = *(const u32*)(row + d);
        } else if constexpr (VW == 4) {
            uint2 t = *(const uint2*)(row + d);
            ua[0] = t.x; ua[1] = t.y;
        } else {
            uint4 t = *(const uint4*)(row + d);
            ua[0] = t.x; ua[1] = t.y; ua[2] = t.z; ua[3] = t.w;
        }
        #pragma unroll
        for (int j = 0; j < VW / 2; j++) {
            float h0 = h2f((u16)(ua[j] & 0xffffu)), h1 = h2f((u16)(ua[j] >> 16));
            ss += h0 * wsrc[d + 2 * j] + h1 * wsrc[d + 2 * j + 1];
            sd += h0 * wdst[d + 2 * j] + h1 * wdst[d + 2 * j + 1];
        }
    }
    #pragma unroll
    for (int off = 32; off; off >>= 1) {
        ss += __shfl_down(ss, off, 64);
        sd += __shfl_down(sd, off, 64);
    }
    if (lane == 0) { s_src[v] = ss; s_dst[v] = sd; }
}

// ---------------- edge softmax: alpha per edge (one wave per node) ----------------

__global__ __launch_bounds__(256) void k_alpha(const int* __restrict__ row_ptr,
                                               const int* __restrict__ col,
                                               const float* __restrict__ s_src,
                                               const float* __restrict__ s_dst,
                                               float* __restrict__ alpha) {
    int grp = threadIdx.x >> 6;
    int lane = threadIdx.x & 63;
    int v = blockIdx.x * 4 + grp;
    if (v >= NN) return;
    int st = row_ptr[v], en = row_ptr[v + 1];
    float sd = s_dst[v];
    float mx = -INFINITY;
    for (int p = st + lane; p < en; p += 64)
        mx = fmaxf(mx, lrelu_att(s_src[col[p]] + sd));
    #pragma unroll
    for (int off = 32; off; off >>= 1) mx = fmaxf(mx, __shfl_xor(mx, off, 64));
    float sum = 0.f;
    for (int p = st + lane; p < en; p += 64)
        sum += __expf(lrelu_att(s_src[col[p]] + sd) - mx);
    #pragma unroll
    for (int off = 32; off; off >>= 1) sum += __shfl_xor(sum, off, 64);
    float inv = 1.0f / (sum + 1e-16f);
    for (int p = st + lane; p < en; p += 64)
        alpha[p] = __expf(lrelu_att(s_src[col[p]] + sd) - mx) * inv;
}

// ---------------- monolithic gather: agg[v] = sum_e alpha_e * h[col_e] ----------------
// alpha precomputed; 4-edge unroll for MLP. CPT=4 (uint4, 16B/lane/edge) for l=3.

template <int TPN, int CPT>
__global__ __launch_bounds__(256) void k_agg2(const u16* __restrict__ h,
                                              const int* __restrict__ row_ptr,
                                              const int* __restrict__ col,
                                              const float* __restrict__ alpha,
                                              u16* __restrict__ agg, int din) {
    constexpr int NPB = 256 / TPN;
    int grp = threadIdx.x / TPN;
    int lane = threadIdx.x % TPN;
    int v = blockIdx.x * NPB + grp;
    if (v >= NN) return;
    int st = row_ptr[v], en = row_ptr[v + 1];
    int d0 = lane * 2 * CPT;
    const u16* hb = h + d0;
    float acc[2 * CPT];
    #pragma unroll
    for (int i = 0; i < 2 * CPT; i++) acc[i] = 0.f;

    auto ld = [&](int c, u32* t) {
        if constexpr (CPT == 1) {
            t[0] = *(const u32*)(hb + (size_t)c * din);
        } else if constexpr (CPT == 2) {
            uint2 u = *(const uint2*)(hb + (size_t)c * din);
            t[0] = u.x; t[1] = u.y;
        } else {
            uint4 u = *(const uint4*)(hb + (size_t)c * din);
            t[0] = u.x; t[1] = u.y; t[2] = u.z; t[3] = u.w;
        }
    };

    int p = st;
    for (; p + 4 <= en; p += 4) {
        float aa[4];
        u32 t[4][CPT];
        #pragma unroll
        for (int e = 0; e < 4; e++) {
            int c = col[p + e];
            aa[e] = alpha[p + e];
            ld(c, t[e]);
        }
        #pragma unroll
        for (int e = 0; e < 4; e++)
            #pragma unroll
            for (int j = 0; j < CPT; j++) {
                acc[2 * j]     += aa[e] * h2f((u16)(t[e][j] & 0xffffu));
                acc[2 * j + 1] += aa[e] * h2f((u16)(t[e][j] >> 16));
            }
    }
    for (; p < en; p++) {
        float a = alpha[p];
        u32 t[CPT];
        ld(col[p], t);
        #pragma unroll
        for (int j = 0; j < CPT; j++) {
            acc[2 * j]     += a * h2f((u16)(t[j] & 0xffffu));
            acc[2 * j + 1] += a * h2f((u16)(t[j] >> 16));
        }
    }

    u32 o[CPT];
    #pragma unroll
    for (int j = 0; j < CPT; j++)
        o[j] = (u32)f2h(acc[2 * j]) | ((u32)f2h(acc[2 * j + 1]) << 16);
    if constexpr (CPT == 1) {
        *(u32*)(agg + (size_t)v * din + d0) = o[0];
    } else if constexpr (CPT == 2) {
        uint2 ov; ov.x = o[0]; ov.y = o[1];
        *(uint2*)(agg + (size_t)v * din + d0) = ov;
    } else {
        uint4 ov; ov.x = o[0]; ov.y = o[1]; ov.z = o[2]; ov.w = o[3];
        *(uint4*)(agg + (size_t)v * din + d0) = ov;
    }
}

// layer-0 variant: din=9, f32 input; one wave per node, lanes 0..8 gather.
__global__ __launch_bounds__(256) void k_agg0_fused(const float* __restrict__ x,
                                                    const int* __restrict__ row_ptr,
                                                    const int* __restrict__ col,
                                                    const float* __restrict__ s_src,
                                                    const float* __restrict__ s_dst,
                                                    float* __restrict__ agg0) {
    __shared__ float sm[4 * 2];
    int grp = threadIdx.x >> 6;
    int lane = threadIdx.x & 63;
    int v = blockIdx.x * 4 + grp;
    bool valid = v < NN;
    int st = 0, en = 0;
    float sd = 0.f;
    if (valid) { st = row_ptr[v]; en = row_ptr[v + 1]; sd = s_dst[v]; }
    float mx = -INFINITY;
    if (valid) {
        for (int p = st + lane; p < en; p += 64)
            mx = fmaxf(mx, lrelu_att(s_src[col[p]] + sd));
    }
    #pragma unroll
    for (int off = 32; off; off >>= 1) mx = fmaxf(mx, __shfl_xor(mx, off, 64));
    float sum = 0.f;
    if (valid) {
        for (int p = st + lane; p < en; p += 64)
            sum += __expf(lrelu_att(s_src[col[p]] + sd) - mx);
    }
    #pragma unroll
    for (int off = 32; off; off >>= 1) sum += __shfl_xor(sum, off, 64);
    if (lane == 0) { sm[grp * 2] = mx; sm[grp * 2 + 1] = 1.0f / (sum + 1e-16f); }
    __syncthreads();
    if (!valid || lane >= 9) return;
    float m = sm[grp * 2], inv = sm[grp * 2 + 1];
    float acc = 0.f;
    for (int p = st; p < en; p++) {
        int c = col[p];
        float a = __expf(lrelu_att(s_src[c] + sd) - m);
        acc += a * x[(size_t)c * 9 + lane];
    }
    agg0[(size_t)v * 9 + lane] = acc * inv;
}

// ---------------- layer 0 GEMM: agg0[NN][9] f32 @ W0[9][128] + bias + lrelu ----------------

__global__ __launch_bounds__(256) void k_gemm0(const float* __restrict__ agg0,
                                               const float* __restrict__ W,
                                               const float* __restrict__ bias,
                                               u16* __restrict__ out) {
    __shared__ float Ws[9 * 128];
    for (int i = threadIdx.x; i < 9 * 128; i += 256) Ws[i] = W[i];
    __syncthreads();
    int node = blockIdx.x * 2 + (threadIdx.x >> 7);
    int n = threadIdx.x & 127;
    if (node >= NN) return;
    const float* xr = agg0 + (size_t)node * 9;
    float acc = bias[n];
    #pragma unroll
    for (int k = 0; k < 9; k++) acc += xr[k] * Ws[k * 128 + n];
    acc = (acc > 0.f) ? acc : NEG_ACT * acc;
    out[(size_t)node * 128 + n] = f2h(acc);
}

// ---------------- 128x128 MFMA GEMM (layers 1,2) ----------------

#define BM 128
#define BK 32

__global__ __launch_bounds__(256) void k_gemm_f16(const u16* __restrict__ A,
                                                  const u16* __restrict__ B,
                                                  const float* __restrict__ bias,
                                                  u16* __restrict__ C,
                                                  int K, int ldC, int NC, int ntx) {
    int nwg = gridDim.x;
    int b = blockIdx.x;
    int q = nwg >> 3, r = nwg & 7;
    int xcd = b & 7, idx = b >> 3;
    int wg = (xcd < r ? xcd * (q + 1) : r * (q + 1) + (xcd - r) * q) + idx;
    int row0 = (wg / ntx) * BM;
    int col0 = (wg % ntx) * BM;

    __shared__ u16 lds[2][2][BM * BK];   // 32 KiB
    int tid = threadIdx.x;
    int lane = tid & 63, w = tid >> 6;
    int wr = w >> 1, wc = w & 1;

    f32x4 acc[4][4];
    #pragma unroll
    for (int m = 0; m < 4; m++)
        #pragma unroll
        for (int n = 0; n < 4; n++)
            #pragma unroll
            for (int rr2 = 0; rr2 < 4; rr2++) acc[m][n][rr2] = 0.f;

    int nt = K / BK;

    auto stage = [&](int buf, int t) {
        int k0 = t * BK;
        #pragma unroll
        for (int c = 0; c < 2; c++) {
            int idx2 = tid + c * 256;           // 0..511
            int rr2 = idx2 >> 2, kc = idx2 & 3;
            int kcs = kc ^ (rr2 & 3);           // pre-swizzled global source
            gl_lds16(A + (size_t)(row0 + rr2) * K + k0 + kcs * 8, &lds[buf][0][idx2 * 8]);
            gl_lds16(B + (size_t)(col0 + rr2) * K + k0 + kcs * 8, &lds[buf][1][idx2 * 8]);
        }
    };

    auto compute = [&](int buf) {
        const u16* As = &lds[buf][0][0];
        const u16* Bs = &lds[buf][1][0];
        int kg = lane >> 4, rl = lane & 15;
        half8 af[4], bfr[4];
        #pragma unroll
        for (int m = 0; m < 4; m++) {
            int rr2 = wr * 64 + m * 16 + rl;
            af[m] = *(const half8*)(As + rr2 * BK + (kg ^ (rr2 & 3)) * 8);
        }
        #pragma unroll
        for (int n = 0; n < 4; n++) {
            int rr2 = wc * 64 + n * 16 + rl;
            bfr[n] = *(const half8*)(Bs + rr2 * BK + (kg ^ (rr2 & 3)) * 8);
        }
        #pragma unroll
        for (int m = 0; m < 4; m++)
            #pragma unroll
            for (int n = 0; n < 4; n++)
                acc[m][n] = __builtin_amdgcn_mfma_f32_16x16x32_f16(af[m], bfr[n], acc[m][n], 0, 0, 0);
    };

    stage(0, 0);
    __syncthreads();
    for (int t = 0; t < nt; t++) {
        if (t + 1 < nt) stage((t + 1) & 1, t + 1);
        compute(t & 1);
        __syncthreads();
    }

    u16* ep = ((u16*)lds) + w * (32 * 72);
    int kg = lane >> 4, rl = lane & 15;
    int rrow = lane >> 3;
    int c8 = (lane & 7) * 8;
    #pragma unroll
    for (int half = 0; half < 2; half++) {
        #pragma unroll
        for (int m2 = 0; m2 < 2; m2++) {
            int m = half * 2 + m2;
            #pragma unroll
            for (int n = 0; n < 4; n++) {
                int colg = col0 + wc * 64 + n * 16 + rl;
                float bb = (colg < NC) ? bias[colg] : 0.f;
                #pragma unroll
                for (int rr2 = 0; rr2 < 4; rr2++) {
                    float o = acc[m][n][rr2] + bb;
                    o = (o > 0.f) ? o : NEG_ACT * o;
                    ep[(m2 * 16 + kg * 4 + rr2) * 72 + n * 16 + rl] = f2h(o);
                }
            }
        }
        #pragma unroll
        for (int it = 0; it < 4; it++) {
            int rloc = it * 8 + rrow;
            half8 vv = *(const half8*)(ep + rloc * 72 + c8);
            int rowg = row0 + wr * 64 + half * 32 + rloc;
            *(half8*)(C + (size_t)rowg * ldC + col0 + wc * 64 + c8) = vv;
        }
    }
}

// ---------------- 256x256 MFMA GEMM: BK=32, TRIPLE buffer, ONE barrier/K-tile (layer 3) ----------------

__global__ __launch_bounds__(1024, 4) void k_gemm256(const u16* __restrict__ A,
                                                     const u16* __restrict__ B,
                                                     const float* __restrict__ bias,
                                                     u16* __restrict__ C,
                                                     int K, int ldC, int NC, int ntx, int M) {
    __shared__ u16 sMem[49152];   // 3 bufs x (A 8192 + B 8192) u16 = 96 KiB

    int nwg = gridDim.x, b = blockIdx.x;
    int q = nwg >> 3, r = nwg & 7;
    int xcd = b & 7, bidx = b >> 3;
    int wg = (xcd < r ? xcd * (q + 1) : r * (q + 1) + (xcd - r) * q) + bidx;
    int row0 = (wg / ntx) * 256;
    int col0 = (wg % ntx) * 256;

    int tid = threadIdx.x;
    int w = tid >> 6, lane = tid & 63;
    int wm = w >> 2, wn = w & 3;           // 4 x 4 wave grid, 64x64 out per wave
    int rl = lane & 15, kg = lane >> 4;
    int ksl = (kg ^ ((rl >> 1) & 3)) * 8;  // swizzled read slot offset (u16 units)

    f32x4 acc[4][4];
    #pragma unroll
    for (int m = 0; m < 4; m++)
        #pragma unroll
        for (int n = 0; n < 4; n++)
            #pragma unroll
            for (int i = 0; i < 4; i++) acc[m][n][i] = 0.f;

    {
        int rr = tid >> 2, s = tid & 3;
        int ss = s ^ ((rr >> 1) & 3);
        int ra = row0 + rr; ra = (ra < M) ? ra : (M - 1);
        const u16* aSrc0 = A + (size_t)ra * K + ss * 8;
        const u16* bSrc0 = B + (size_t)(col0 + rr) * K + ss * 8;
        u16* dstA = sMem + tid * 8;
        u16* dstB = sMem + 8192 + tid * 8;

        auto stage = [&](int t, int bf2) {
            gl_lds16(aSrc0 + t * 32, dstA + bf2 * 16384);
            gl_lds16(bSrc0 + t * 32, dstB + bf2 * 16384);
        };

        half8 af[4], bf[4];
        auto ldAB = [&](int bf2) {
            const u16* Ab = sMem + bf2 * 16384;
            const u16* Bb = Ab + 8192;
            #pragma unroll
            for (int i = 0; i < 4; i++)
                af[i] = *(const half8*)(Ab + (wm * 64 + i * 16 + rl) * 32 + ksl);
            #pragma unroll
            for (int i = 0; i < 4; i++)
                bf[i] = *(const half8*)(Bb + (wn * 64 + i * 16 + rl) * 32 + ksl);
        };

        int nt = K >> 5;    // K-tiles of 32; nt >= 8 for our shapes

        stage(0, 0); stage(1, 1);
        __builtin_amdgcn_sched_barrier(0);
        asm volatile("s_waitcnt vmcnt(2)" ::: "memory");
        __builtin_amdgcn_s_barrier();
        __builtin_amdgcn_sched_barrier(0);

        int rb = 0;
        for (int t = 0; t < nt; t++) {
            int sb = rb + 2; if (sb >= 3) sb -= 3;
            if (t + 2 < nt) stage(t + 2, sb);
            ldAB(rb);
            __builtin_amdgcn_s_setprio(1);
            #pragma unroll
            for (int i = 0; i < 4; i++)
                #pragma unroll
                for (int n = 0; n < 4; n++)
                    acc[i][n] = __builtin_amdgcn_mfma_f32_16x16x32_f16(af[i], bf[n], acc[i][n], 0, 0, 0);
            __builtin_amdgcn_s_setprio(0);
            __builtin_amdgcn_sched_barrier(0);
            if (t + 2 < nt)      asm volatile("s_waitcnt vmcnt(2)" ::: "memory");
            else if (t + 1 < nt) asm volatile("s_waitcnt vmcnt(0)" ::: "memory");
            __builtin_amdgcn_s_barrier();
            __builtin_amdgcn_sched_barrier(0);
            rb = (rb == 2) ? 0 : rb + 1;
        }
    }

    // epilogue: per-wave private 32x72 LDS staging region, coalesced half8 stores
    u16* ep = sMem + w * (32 * 72);
    float bv[4];
    #pragma unroll
    for (int n = 0; n < 4; n++) {
        int colg = col0 + wn * 64 + n * 16 + rl;
        bv[n] = (colg < NC) ? bias[colg] : 0.f;
    }
    int rrow = lane >> 3, c8 = (lane & 7) * 8;
    #pragma unroll
    for (int mh = 0; mh < 2; mh++) {
        #pragma unroll
        for (int msub = 0; msub < 2; msub++) {
            int m = mh * 2 + msub;
            #pragma unroll
            for (int n = 0; n < 4; n++) {
                #pragma unroll
                for (int rg = 0; rg < 4; rg++) {
                    float o = acc[m][n][rg] + bv[n];
                    o = (o > 0.f) ? o : NEG_ACT * o;
                    ep[(msub * 16 + kg * 4 + rg) * 72 + n * 16 + rl] = f2h(o);
                }
            }
        }
        #pragma unroll
        for (int it = 0; it < 4; it++) {
            int rloc = it * 8 + rrow;
            half8 vv = *(const half8*)(ep + rloc * 72 + c8);
            int rowg = row0 + wm * 64 + mh * 32 + rloc;
            if (rowg < M)
                *(half8*)(C + (size_t)rowg * ldC + col0 + wn * 64 + c8) = vv;
        }
    }
}

// ---------------- GraphNorm fused: stats + apply in ONE kernel (l<3) ----------------

__global__ __launch_bounds__(256) void k_gn_fused(const u16* __restrict__ h,
                           const int* __restrict__ gstart,
                           const float* __restrict__ ms, const float* __restrict__ gam,
                           const float* __restrict__ bet, u16* __restrict__ out, int ld) {
    int g = blockIdx.x;
    int c0 = blockIdx.y * 128;
    int ct = threadIdx.x & 15, rg = threadIdx.x >> 4;
    int d0 = c0 + ct * 8;
    int st = gstart[g], en = gstart[g + 1];
    float inv = 1.0f / (float)(en - st);
    float s[8], qq[8];
    #pragma unroll
    for (int i = 0; i < 8; i++) { s[i] = 0.f; qq[i] = 0.f; }
    for (int r = st + rg; r < en; r += 16) {
        uint4 u = *(const uint4*)(h + (size_t)r * ld + d0);
        u32 ua[4] = {u.x, u.y, u.z, u.w};
        #pragma unroll
        for (int j = 0; j < 4; j++) {
            float v0 = h2f((u16)(ua[j] & 0xffffu)), v1 = h2f((u16)(ua[j] >> 16));
            s[2 * j] += v0; s[2 * j + 1] += v1;
            qq[2 * j] += v0 * v0; qq[2 * j + 1] += v1 * v1;
        }
    }
    __shared__ float Ls[16][128], Lq[16][128];
    #pragma unroll
    for (int i = 0; i < 8; i++) { Ls[rg][ct * 8 + i] = s[i]; Lq[rg][ct * 8 + i] = qq[i]; }
    __syncthreads();
    int tid = threadIdx.x;
    if (tid < 128) {
        float ss = 0.f, sq = 0.f;
        #pragma unroll
        for (int r2 = 1; r2 < 16; r2++) { ss += Ls[r2][tid]; sq += Lq[r2][tid]; }
        Ls[0][tid] += ss; Lq[0][tid] += sq;
    }
    __syncthreads();
    float sub[8], sc[8], bv[8];
    #pragma unroll
    for (int i = 0; i < 8; i++) {
        int cl = ct * 8 + i, d = d0 + i;
        float msv = ms[d];
        float mean = Ls[0][cl] * inv;
        float q2   = Lq[0][cl] * inv;
        float var  = fmaxf(q2 - (2.f * msv - msv * msv) * mean * mean, 0.f);
        sub[i] = msv * mean;
        sc[i]  = gam[d] * rsqrtf(var + EPS_GN);
        bv[i]  = bet[d];
    }
    for (int r = st + rg; r < en; r += 16) {
        uint4 u = *(const uint4*)(h + (size_t)r * ld + d0);
        u32 ua[4] = {u.x, u.y, u.z, u.w};
        uint4 wv4;
        u32 wo[4];
        #pragma unroll
        for (int j = 0; j < 4; j++) {
            float o0 = (h2f((u16)(ua[j] & 0xffffu)) - sub[2 * j]) * sc[2 * j] + bv[2 * j];
            float o1 = (h2f((u16)(ua[j] >> 16)) - sub[2 * j + 1]) * sc[2 * j + 1] + bv[2 * j + 1];
            wo[j] = (u32)f2h(o0) | ((u32)f2h(o1) << 16);
        }
        wv4.x = wo[0]; wv4.y = wo[1]; wv4.z = wo[2]; wv4.w = wo[3];
        *(uint4*)(out + (size_t)r * ld + d0) = wv4;
    }
}

// l=3: SINGLE-PASS stats + pooling. Normalized o = (v - ms*mean)*sc + beta is a
// monotone affine map of raw v, so mean-pool and max-pool are closed-form in
// (sum, sumsq, min, max) — no second read pass.

__global__ __launch_bounds__(256) void k_gn_poolf(const u16* __restrict__ h,
                           const int* __restrict__ gstart,
                           const float* __restrict__ ms, const float* __restrict__ gam,
                           const float* __restrict__ bet, float* __restrict__ out,
                           int dout, int ld) {
    int g = blockIdx.x;
    int c0 = blockIdx.y * 128;
    int ct = threadIdx.x & 15, rg = threadIdx.x >> 4;
    int d0 = c0 + ct * 8;
    int st = gstart[g], en = gstart[g + 1];
    float inv = 1.0f / (float)(en - st);
    float s[8], qq[8], mn[8], mx[8];
    #pragma unroll
    for (int i = 0; i < 8; i++) { s[i] = 0.f; qq[i] = 0.f; mn[i] = INFINITY; mx[i] = -INFINITY; }
    for (int r = st + rg; r < en; r += 16) {
        uint4 u = *(const uint4*)(h + (size_t)r * ld + d0);
        u32 ua[4] = {u.x, u.y, u.z, u.w};
        #pragma unroll
        for (int j = 0; j < 4; j++) {
            float v0 = h2f((u16)(ua[j] & 0xffffu)), v1 = h2f((u16)(ua[j] >> 16));
            s[2 * j] += v0; s[2 * j + 1] += v1;
            qq[2 * j] += v0 * v0; qq[2 * j + 1] += v1 * v1;
            mn[2 * j] = fminf(mn[2 * j], v0); mn[2 * j + 1] = fminf(mn[2 * j + 1], v1);
            mx[2 * j] = fmaxf(mx[2 * j], v0); mx[2 * j + 1] = fmaxf(mx[2 * j + 1], v1);
        }
    }
    __shared__ float Ls[16][128], Lq[16][128], Ln[16][128], Lx[16][128];
    #pragma unroll
    for (int i = 0; i < 8; i++) {
        Ls[rg][ct * 8 + i] = s[i]; Lq[rg][ct * 8 + i] = qq[i];
        Ln[rg][ct * 8 + i] = mn[i]; Lx[rg][ct * 8 + i] = mx[i];
    }
    __syncthreads();
    int tid = threadIdx.x;
    if (tid < 128) {
        float ss = 0.f, sq = 0.f, amn = INFINITY, amx = -INFINITY;
        #pragma unroll
        for (int r2 = 0; r2 < 16; r2++) {
            ss += Ls[r2][tid]; sq += Lq[r2][tid];
            amn = fminf(amn, Ln[r2][tid]); amx = fmaxf(amx, Lx[r2][tid]);
        }
        int d = c0 + tid;
        if (d < dout) {
            float msv = ms[d];
            float mean = ss * inv;
            float q2   = sq * inv;
            float var  = fmaxf(q2 - (2.f * msv - msv * msv) * mean * mean, 0.f);
            float sc   = gam[d] * rsqrtf(var + EPS_GN);
            float off  = bet[d] - msv * mean * sc;
            out[(size_t)g * 2 * dout + d] = (mean - msv * mean) * sc + bet[d];
            float mval = (sc >= 0.f) ? amx : amn;
            out[(size_t)g * 2 * dout + dout + d] = mval * sc + off;
        }
    }
}

// ---------------- launch ----------------

extern "C" void kernel_launch(void* const* d_in, const int* in_sizes, int n_in,
                              void* d_out, int out_size, void* d_ws, size_t ws_size,
                              hipStream_t stream) {
    const float* x = (const float*)d_in[0];
    const int* ei = (const int*)d_in[1];
    const int* batch = (const int*)d_in[2];
    const float *Wl[4], *Asr[4], *Ads[4], *Bi[4], *Ga[4], *Be[4], *Ms[4];
    for (int l = 0; l < 4; l++) {
        int b = 3 + 7 * l;
        Wl[l]  = (const float*)d_in[b];
        Asr[l] = (const float*)d_in[b + 1];
        Ads[l] = (const float*)d_in[b + 2];
        Bi[l]  = (const float*)d_in[b + 3];
        Ga[l]  = (const float*)d_in[b + 4];
        Be[l]  = (const float*)d_in[b + 5];
        Ms[l]  = (const float*)d_in[b + 6];
    }

    char* ws = (char*)d_ws;
    size_t off = 0;
    auto alloc = [&](size_t bytes) -> char* {
        char* p = ws + off;
        off += (bytes + 255) & ~(size_t)255;
        return p;
    };
    u16*   actA   = (u16*)alloc((size_t)MPAD * 512 * 2);    // normalized h (layers 0-2)
    u16*   actB   = (u16*)alloc((size_t)MPAD * 1536 * 2);   // GEMM output
    u16*   agg    = (u16*)alloc((size_t)MPAD * 512 * 2);    // aggregated pre-projection (f16)
    float* agg0   = (float*)alloc((size_t)NN * 9 * 4);      // layer-0 aggregated (f32)
    u16*   WbTall = (u16*)alloc((size_t)(256 * 128 + 512 * 256 + 1536 * 512) * 2);
    float* wsrcA  = (float*)alloc((size_t)4 * 512 * 4);
    float* wdstA  = (float*)alloc((size_t)4 * 512 * 4);
    float* s_src  = (float*)alloc((size_t)NN * 4);
    float* s_dst  = (float*)alloc((size_t)NN * 4);
    float* alpha  = (float*)alloc((size_t)ET * 4);
    int* row_ptr  = (int*)alloc((size_t)(NN + 1) * 4);
    int* cursor   = (int*)alloc((size_t)NN * 4);
    int* colA     = (int*)alloc((size_t)ET * 4);
    int* counts   = (int*)alloc((size_t)NG * 4);
    int* gstart   = (int*)alloc((size_t)(NG + 1) * 4);
    int* bsum     = (int*)alloc((size_t)NBLK * 4);
    int* boff     = (int*)alloc((size_t)NBLK * 4);

    // --- zero region: deg only ---
    char* zbase = ws + off;
    int* deg      = (int*)alloc((size_t)NN * 4);
    size_t zbytes = (size_t)((ws + off) - zbase);
    hipMemsetAsync(zbase, 0, zbytes, stream);

    k_bounds<<<1, 64, 0, stream>>>(batch, counts, gstart);
    k_deg<<<(ET + 255) / 256, 256, 0, stream>>>(ei, deg);
    k_scan1<<<NBLK, 256, 0, stream>>>(deg, bsum);
    k_scan2<<<1, 256, 0, stream>>>(bsum, boff, row_ptr + NN);
    k_scan3<<<NBLK, 256, 0, stream>>>(deg, boff, row_ptr, cursor);
    k_scatter<<<(ET + 255) / 256, 256, 0, stream>>>(ei, cursor, colA);

    Ptr4 Wp{Wl[0], Wl[1], Wl[2], Wl[3]};
    Ptr4 Ap{Asr[0], Asr[1], Asr[2], Asr[3]};
    Ptr4 Dp{Ads[0], Ads[1], Ads[2], Ads[3]};
    k_wvec_all<<<dim3(512, 4), 256, 0, stream>>>(Wp, Ap, Dp, wsrcA, wdstA);
    k_wbt_all<<<dim3(48, 16, 3), 256, 0, stream>>>(Wp, WbTall);

    const int dims[5] = {9, 128, 256, 512, 1534};
    const size_t wbtOffs[3] = {0, 256 * 128, 256 * 128 + 512 * 256};
    const int RT256 = (MPAD + 255) / 256;   // 79 row tiles for the 256 GEMM

    for (int l = 0; l < 4; l++) {
        int din = dims[l], dout = dims[l + 1];
        int ldo = (dout == 1534) ? 1536 : dout;
        const float* wsrc = wsrcA + l * 512;
        const float* wdst = wdstA + l * 512;

        if (l == 0) {
            k_scores0<<<(NN + 255) / 256, 256, 0, stream>>>(x, wsrc, wdst, s_src, s_dst);
            k_agg0_fused<<<(NN + 3) / 4, 256, 0, stream>>>(x, row_ptr, colA, s_src, s_dst, agg0);
            k_gemm0<<<(NN + 1) / 2, 256, 0, stream>>>(agg0, Wl[0], Bi[0], actB);
        } else {
            if (din == 128)
                k_scores_h<2><<<(NN + 3) / 4, 256, 0, stream>>>(actA, wsrc, wdst, s_src, s_dst, din);
            else if (din == 256)
                k_scores_h<4><<<(NN + 3) / 4, 256, 0, stream>>>(actA, wsrc, wdst, s_src, s_dst, din);
            else
                k_scores_h<8><<<(NN + 3) / 4, 256, 0, stream>>>(actA, wsrc, wdst, s_src, s_dst, din);
            k_alpha<<<(NN + 3) / 4, 256, 0, stream>>>(row_ptr, colA, s_src, s_dst, alpha);
            if (din == 128)
                k_agg2<64, 1><<<(NN + 3) / 4, 256, 0, stream>>>(actA, row_ptr, colA, alpha, agg, din);
            else if (din == 256)
                k_agg2<64, 2><<<(NN + 3) / 4, 256, 0, stream>>>(actA, row_ptr, colA, alpha, agg, din);
            else
                k_agg2<64, 4><<<(NN + 3) / 4, 256, 0, stream>>>(actA, row_ptr, colA, alpha, agg, din);
            if (l <= 2) {
                int ntx = ldo / 128;            // 2 (l=1) or 4 (l=2)
                int nwg = ntx * (MPAD / 128);   // 314 or 628
                k_gemm_f16<<<nwg, 256, 0, stream>>>(agg, WbTall + wbtOffs[l - 1], Bi[l], actB,
                                                    din, ldo, dout, ntx);
            } else {
                int ntx = ldo / 256;            // 6
                int nwg = ntx * RT256;          // 474
                k_gemm256<<<nwg, 1024, 0, stream>>>(agg, WbTall + wbtOffs[l - 1], Bi[l], actB,
                                                    din, ldo, dout, ntx, MPAD);
            }
        }

        if (l < 3)
            k_gn_fused<<<dim3(NG, ldo / 128), 256, 0, stream>>>(actB, gstart,
                                                                Ms[l], Ga[l], Be[l], actA, ldo);
        else
            k_gn_poolf<<<dim3(NG, 12), 256, 0, stream>>>(actB, gstart,
                                                         Ms[3], Ga[3], Be[3], (float*)d_out,
                                                         1534, 1536);
    }
}